// Round 3
// baseline (878.983 us; speedup 1.0000x reference)
//
#include <hip/hip_runtime.h>
#include <math.h>

// ---------------------------------------------------------------------------
// GAT 4-layer forward.
//   CSR build (zero -> hist -> blocked scan(+cursor) -> scatter) per call.
//   Per layer: zero as/ad -> split-bf16 MFMA GEMM with fused alpha epilogue
//   (as/ad via 16-lane shuffle reduce + atomicAdd) -> agg kernel: pass 1
//   lane-parallel softmax stats (m,l), pass 2 gather with precomputed alpha
//   (1 FMA/elem, 2-edge unroll), epilogue emits next layer's bf16 hi/lo A.
// ---------------------------------------------------------------------------

typedef __attribute__((ext_vector_type(8))) __bf16 bf16x8;
typedef __attribute__((ext_vector_type(4))) float floatx4;

__device__ __forceinline__ unsigned short f2bf(float f) {   // RNE
    unsigned int u = __float_as_uint(f);
    u += 0x7fff + ((u >> 16) & 1);
    return (unsigned short)(u >> 16);
}
__device__ __forceinline__ float bf2f(unsigned short u) {
    return __uint_as_float(((unsigned int)u) << 16);
}
__device__ __forceinline__ float lrelu(float e) {
    return (e > 0.f) ? e : 0.2f * e;
}
__device__ __forceinline__ void gload16(const void* g, void* l) {
    __builtin_amdgcn_global_load_lds(
        (const __attribute__((address_space(1))) void*)g,
        (__attribute__((address_space(3))) void*)l, 16, 0, 0);
}

// ---------------------------------------------------------------------------
// CSR build
// ---------------------------------------------------------------------------
static __global__ void zero_int(int* __restrict__ p, int n) {
    int i = blockIdx.x * blockDim.x + threadIdx.x;
    if (i < n) p[i] = 0;
}
static __global__ void zero_float(float* __restrict__ p, int n) {
    int i = blockIdx.x * blockDim.x + threadIdx.x;
    if (i < n) p[i] = 0.f;
}

static __global__ void hist_kernel(const int* __restrict__ ei, int e0, int n_nodes,
                                   int* __restrict__ counts) {
    int e = blockIdx.x * blockDim.x + threadIdx.x;
    int et = e0 + n_nodes;
    if (e >= et) return;
    int d = (e < e0) ? ei[e0 + e] : (e - e0);
    atomicAdd(&counts[d], 1);
}

// single-block blocked scan: row_ptr[i] = exclusive prefix; cursor[i] = same
// (absolute scatter cursor); row_ptr[n] = total.
static __global__ void scan_kernel(const int* __restrict__ counts,
                                   int* __restrict__ row_ptr,
                                   int* __restrict__ cursor, int n) {
    __shared__ int sdata[1024];
    int tid = threadIdx.x;
    int per = (n + 1023) / 1024;
    int start = tid * per;
    int stop = min(start + per, n);
    if (start > n) start = n;
    int s = 0;
    for (int i = start; i < stop; i++) s += counts[i];
    sdata[tid] = s;
    __syncthreads();
    for (int off = 1; off < 1024; off <<= 1) {
        int t = (tid >= off) ? sdata[tid - off] : 0;
        __syncthreads();
        sdata[tid] += t;
        __syncthreads();
    }
    int run = sdata[tid] - s;          // exclusive prefix at chunk start
    for (int i = start; i < stop; i++) {
        row_ptr[i] = run;
        cursor[i] = run;
        run += counts[i];
    }
    if (stop == n) row_ptr[n] = run;   // threads past the end also hold total
}

static __global__ void scatter_kernel(const int* __restrict__ ei, int e0, int n_nodes,
                                      int* __restrict__ cursor,
                                      int* __restrict__ src_sorted) {
    int e = blockIdx.x * blockDim.x + threadIdx.x;
    int et = e0 + n_nodes;
    if (e >= et) return;
    int s, d;
    if (e < e0) { s = ei[e]; d = ei[e0 + e]; } else { s = e - e0; d = s; }
    int pos = atomicAdd(&cursor[d], 1);
    src_sorted[pos] = s;
}

// ---------------------------------------------------------------------------
// hi/lo conversion kernels
// ---------------------------------------------------------------------------
static __global__ void convA_kernel(const float* __restrict__ X,
                                    unsigned short* __restrict__ A, int M, int K) {
    int idx = blockIdx.x * 256 + threadIdx.x;
    if (idx >= M * K) return;
    int m = idx / K, k = idx % K;
    float v = X[idx];
    unsigned short hi = f2bf(v);
    size_t base = (size_t)m * (2 * K);
    A[base + k] = hi;
    A[base + K + k] = f2bf(v - bf2f(hi));
}

// W[K,N] fp32 -> BT'[Npad,3K] bf16 rows = W columns; [0:K)=hi [K:2K)=hi [2K:3K)=lo
static __global__ void convW_kernel(const float* __restrict__ W,
                                    unsigned short* __restrict__ BT,
                                    int K, int N, int Npad) {
    int idx = blockIdx.x * 256 + threadIdx.x;
    if (idx >= Npad * K) return;
    int n = idx / K, k = idx % K;
    float v = (n < N) ? W[(size_t)k * N + n] : 0.f;
    unsigned short hi = f2bf(v);
    unsigned short lo = f2bf(v - bf2f(hi));
    size_t base = (size_t)n * (3 * K);
    BT[base + k] = hi;
    BT[base + K + k] = hi;
    BT[base + 2 * K + k] = lo;
}

// ---------------------------------------------------------------------------
// split-bf16 MFMA GEMM + fused alpha epilogue.
// C[M,N] fp32 = A'[Mpad,2K] x B (BT'[Npad,3K]); segments (hi,hi),(lo,hi),(hi,lo).
// Epilogue: per-wave 64-col chunk is head-aligned (C in {64,128}); lane partial
// dot with a_src/a_dst, 16-lane shuffle reduce, atomicAdd into as/ad.
// ---------------------------------------------------------------------------
#define BM 128
#define BN 128
#define BKK 64

__launch_bounds__(256)
static __global__ void gemm_mfma(const unsigned short* __restrict__ A,
                                 const unsigned short* __restrict__ B,
                                 float* __restrict__ C, int M, int K, int N,
                                 const float* __restrict__ asv,
                                 const float* __restrict__ adv,
                                 float* __restrict__ as_out,
                                 float* __restrict__ ad_out,
                                 int Hh, int Cc) {
    __shared__ __align__(16) unsigned short lds[2 * BM * BKK];   // 16KB A + 16KB B
    const int tid  = threadIdx.x;
    const int lane = tid & 63;
    const int wave = tid >> 6;
    const int r0 = blockIdx.y * BM;
    const int c0 = blockIdx.x * BN;
    const int wm = (wave >> 1) * 64;
    const int wn = (wave & 1) * 64;
    const int q   = lane >> 4;
    const int m16 = lane & 15;

    floatx4 acc[4][4];
#pragma unroll
    for (int i = 0; i < 4; i++)
#pragma unroll
        for (int j = 0; j < 4; j++) acc[i][j] = {0.f, 0.f, 0.f, 0.f};

    const size_t sA = (size_t)(2 * K);
    const size_t sB = (size_t)(3 * K);
    char* ldsb = (char*)lds;

#pragma unroll 1
    for (int seg = 0; seg < 3; seg++) {
        const int aoff = (seg == 1) ? K : 0;
        const int boff = seg * K;
#pragma unroll 1
        for (int k0 = 0; k0 < K; k0 += BKK) {
            __syncthreads();
#pragma unroll
            for (int c = 0; c < 4; c++) {
                int slot = c * 256 + tid;
                int row = slot >> 3;          // 0..127
                int gc  = (slot & 7) ^ (row & 7);
                gload16(A + (size_t)(r0 + row) * sA + aoff + k0 + gc * 8,
                        ldsb + slot * 16);
                gload16(B + (size_t)(c0 + row) * sB + boff + k0 + gc * 8,
                        ldsb + 16384 + slot * 16);
            }
            __syncthreads();
#pragma unroll
            for (int ks = 0; ks < 2; ks++) {
                bf16x8 af[4], bfr[4];
#pragma unroll
                for (int i = 0; i < 4; i++) {
                    int row = wm + i * 16 + m16;
                    int ch  = (q + ks * 4) ^ (row & 7);
                    af[i] = *(const bf16x8*)(ldsb + (row * 8 + ch) * 16);
                }
#pragma unroll
                for (int j = 0; j < 4; j++) {
                    int row = wn + j * 16 + m16;
                    int ch  = (q + ks * 4) ^ (row & 7);
                    bfr[j] = *(const bf16x8*)(ldsb + 16384 + (row * 8 + ch) * 16);
                }
#pragma unroll
                for (int i = 0; i < 4; i++)
#pragma unroll
                    for (int j = 0; j < 4; j++)
                        acc[i][j] = __builtin_amdgcn_mfma_f32_16x16x32_bf16(
                            af[i], bfr[j], acc[i][j], 0, 0, 0);
            }
        }
    }
    // C store. C/D layout: col = lane&15, row = (lane>>4)*4 + reg
#pragma unroll
    for (int i = 0; i < 4; i++)
#pragma unroll
        for (int j = 0; j < 4; j++)
#pragma unroll
            for (int r = 0; r < 4; r++) {
                int row = r0 + wm + i * 16 + q * 4 + r;
                int col = c0 + wn + j * 16 + m16;
                if (row < M && col < N) C[(size_t)row * N + col] = acc[i][j][r];
            }
    // fused alpha: this wave's 64-col chunk [c0+wn, c0+wn+64) is head-uniform.
    if (c0 + wn < N) {
        int head = (c0 + wn) / Cc;
#pragma unroll
        for (int i = 0; i < 4; i++)
#pragma unroll
            for (int r = 0; r < 4; r++) {
                float ps = 0.f, pd = 0.f;
#pragma unroll
                for (int j = 0; j < 4; j++) {
                    int c = c0 + wn + j * 16 + m16;
                    float v = acc[i][j][r];
                    ps = fmaf(v, asv[c], ps);
                    pd = fmaf(v, adv[c], pd);
                }
#pragma unroll
                for (int off = 1; off < 16; off <<= 1) {
                    ps += __shfl_xor(ps, off);
                    pd += __shfl_xor(pd, off);
                }
                if (m16 == 0) {
                    int row = r0 + wm + i * 16 + q * 4 + r;
                    if (row < M) {
                        atomicAdd(&as_out[(size_t)row * Hh + head], ps);
                        atomicAdd(&ad_out[(size_t)row * Hh + head], pd);
                    }
                }
            }
    }
}

// ---------------------------------------------------------------------------
// aggregation: one wave/node. Pass 1: lane-parallel softmax stats (m,l) per
// head. Pass 2: gather with alpha applied directly (1 FMA/elem), 2-edge
// unroll. Epilogue: bias+relu, bf16 hi/lo (next layer A) or fp32 out.
// ---------------------------------------------------------------------------
template <int H, int C, bool BF16OUT>
__launch_bounds__(256)
static __global__ void agg_kernel(const float* __restrict__ h,
                                  const float* __restrict__ as_arr,
                                  const float* __restrict__ ad_arr,
                                  const int* __restrict__ row_ptr,
                                  const int* __restrict__ src_sorted,
                                  const float* __restrict__ bias,
                                  float* __restrict__ outf,
                                  unsigned short* __restrict__ outb, int n_nodes) {
    constexpr int R = H * C / 64;
    constexpr int G = 64 / H;
    constexpr int K = H * C;
    int wave = threadIdx.x >> 6;
    int lane = threadIdx.x & 63;
    int n = blockIdx.x * 4 + wave;
    if (n >= n_nodes) return;
    int beg = row_ptr[n], end = row_ptr[n + 1];

    // ---- pass 1: per-head m, l (lane-parallel over edges) ----
    float ad_h[H], m_h[H], l_h[H];
#pragma unroll
    for (int hh = 0; hh < H; hh++) {
        ad_h[hh] = ad_arr[(size_t)n * H + hh];
        m_h[hh] = -INFINITY;
        l_h[hh] = 0.f;
    }
    for (int base = beg; base < end; base += 64) {
        int j = base + lane;
        bool ok = j < end;
        float e_h[H];
        if (ok) {
            int s = src_sorted[j];
            if constexpr (H == 4) {
                float4 a = ((const float4*)as_arr)[s];
                e_h[0] = lrelu(a.x + ad_h[0]);
                e_h[1] = lrelu(a.y + ad_h[1]);
                e_h[2] = lrelu(a.z + ad_h[2]);
                e_h[3] = lrelu(a.w + ad_h[3]);
            } else {
                e_h[0] = lrelu(as_arr[s] + ad_h[0]);
            }
        } else {
#pragma unroll
            for (int hh = 0; hh < H; hh++) e_h[hh] = -INFINITY;
        }
#pragma unroll
        for (int hh = 0; hh < H; hh++) {
            float cm = e_h[hh];
#pragma unroll
            for (int off = 1; off < 64; off <<= 1) cm = fmaxf(cm, __shfl_xor(cm, off));
            float newm = fmaxf(m_h[hh], cm);
            float p = ok ? __expf(e_h[hh] - newm) : 0.f;
#pragma unroll
            for (int off = 1; off < 64; off <<= 1) p += __shfl_xor(p, off);
            l_h[hh] = l_h[hh] * __expf(m_h[hh] - newm) + p;
            m_h[hh] = newm;
        }
    }
    int myh = lane / G;
    float mm, adm, inv;
    if constexpr (H == 4) {
        mm  = m_h[0];  mm  = (myh == 1) ? m_h[1] : mm;  mm  = (myh == 2) ? m_h[2] : mm;  mm  = (myh == 3) ? m_h[3] : mm;
        float ll = l_h[0]; ll = (myh == 1) ? l_h[1] : ll; ll = (myh == 2) ? l_h[2] : ll; ll = (myh == 3) ? l_h[3] : ll;
        adm = ad_h[0]; adm = (myh == 1) ? ad_h[1] : adm; adm = (myh == 2) ? ad_h[2] : adm; adm = (myh == 3) ? ad_h[3] : adm;
        inv = 1.f / ll;
    } else {
        mm = m_h[0]; adm = ad_h[0]; inv = 1.f / l_h[0];
    }

    // ---- pass 2: gather with precomputed alpha ----
    float acc[R];
#pragma unroll
    for (int r = 0; r < R; r++) acc[r] = 0.f;

    int j = beg;
    for (; j + 1 < end; j += 2) {
        int s0 = src_sorted[j];
        int s1 = src_sorted[j + 1];
        float w0 = __expf(lrelu(as_arr[(size_t)s0 * H + myh] + adm) - mm) * inv;
        float w1 = __expf(lrelu(as_arr[(size_t)s1 * H + myh] + adm) - mm) * inv;
        const float* h0 = h + (size_t)s0 * K + lane * R;
        const float* h1 = h + (size_t)s1 * K + lane * R;
        if constexpr (R >= 4) {
#pragma unroll
            for (int qq = 0; qq < R / 4; qq++) {
                float4 v0 = ((const float4*)h0)[qq];
                float4 v1 = ((const float4*)h1)[qq];
                acc[qq * 4 + 0] += w0 * v0.x + w1 * v1.x;
                acc[qq * 4 + 1] += w0 * v0.y + w1 * v1.y;
                acc[qq * 4 + 2] += w0 * v0.z + w1 * v1.z;
                acc[qq * 4 + 3] += w0 * v0.w + w1 * v1.w;
            }
        } else {
#pragma unroll
            for (int r = 0; r < R; r++) acc[r] += w0 * h0[r] + w1 * h1[r];
        }
    }
    if (j < end) {
        int s0 = src_sorted[j];
        float w0 = __expf(lrelu(as_arr[(size_t)s0 * H + myh] + adm) - mm) * inv;
        const float* h0 = h + (size_t)s0 * K + lane * R;
        if constexpr (R >= 4) {
#pragma unroll
            for (int qq = 0; qq < R / 4; qq++) {
                float4 v0 = ((const float4*)h0)[qq];
                acc[qq * 4 + 0] += w0 * v0.x;
                acc[qq * 4 + 1] += w0 * v0.y;
                acc[qq * 4 + 2] += w0 * v0.z;
                acc[qq * 4 + 3] += w0 * v0.w;
            }
        } else {
#pragma unroll
            for (int r = 0; r < R; r++) acc[r] += w0 * h0[r];
        }
    }

#pragma unroll
    for (int r = 0; r < R; r++) {
        float v = acc[r] + bias[lane * R + r];
        v = fmaxf(v, 0.f);                            // relu (all 4 layers)
        if constexpr (BF16OUT) {
            unsigned short hi = f2bf(v);
            size_t base = (size_t)n * (2 * K) + lane * R + r;
            outb[base] = hi;
            outb[base + K] = f2bf(v - bf2f(hi));
        } else {
            outf[(size_t)n * K + lane * R + r] = v;
        }
    }
}

// ---------------------------------------------------------------------------

static inline size_t align_up(size_t x) { return (x + 255) & ~(size_t)255; }

extern "C" void kernel_launch(void* const* d_in, const int* in_sizes, int n_in,
                              void* d_out, int out_size, void* d_ws, size_t ws_size,
                              hipStream_t stream) {
    const float* x   = (const float*)d_in[0];
    const int*   ei  = (const int*)d_in[1];
    const float* W1  = (const float*)d_in[2];
    const float* a1s = (const float*)d_in[3];
    const float* a1d = (const float*)d_in[4];
    const float* b1  = (const float*)d_in[5];
    const float* W2  = (const float*)d_in[6];
    const float* a2s = (const float*)d_in[7];
    const float* a2d = (const float*)d_in[8];
    const float* b2  = (const float*)d_in[9];
    const float* W3  = (const float*)d_in[10];
    const float* a3s = (const float*)d_in[11];
    const float* a3d = (const float*)d_in[12];
    const float* b3  = (const float*)d_in[13];
    const float* W4  = (const float*)d_in[14];
    const float* a4s = (const float*)d_in[15];
    const float* a4d = (const float*)d_in[16];
    const float* b4  = (const float*)d_in[17];

    const int n  = in_sizes[0] / 256;    // 30000
    const int e0 = in_sizes[1] / 2;      // 480000
    const int et = e0 + n;
    const int Mpad = ((n + 127) / 128) * 128;   // 30080

    // workspace layout (~130 MB)
    char* w = (char*)d_ws;
    unsigned short* slotA = (unsigned short*)w;  w += align_up((size_t)Mpad * 1024 * 2);
    float* hbuf = (float*)w;                     w += align_up((size_t)n * 512 * 4);
    unsigned short* WT1 = (unsigned short*)w;    w += align_up((size_t)512 * 768 * 2);
    unsigned short* WT2 = (unsigned short*)w;    w += align_up((size_t)512 * 1536 * 2);
    unsigned short* WT3 = (unsigned short*)w;    w += align_up((size_t)256 * 1536 * 2);
    unsigned short* WT4 = (unsigned short*)w;    w += align_up((size_t)128 * 768 * 2);
    float* as_b = (float*)w;                     w += align_up((size_t)n * 4 * 4);
    float* ad_b = (float*)w;                     w += align_up((size_t)n * 4 * 4);
    int* row_ptr = (int*)w;                      w += align_up((size_t)(n + 1) * 4);
    int* counts  = (int*)w;                      w += align_up((size_t)n * 4);
    int* cursor  = (int*)w;                      w += align_up((size_t)n * 4);
    int* src_sorted = (int*)w;                   w += align_up((size_t)et * 4);
    (void)ws_size;

    dim3 blk(256);
    int nodeblocks = (n + 3) / 4;

    // ---- CSR build ----
    zero_int<<<(n + 255) / 256, 256, 0, stream>>>(counts, n);
    hist_kernel<<<(et + 255) / 256, 256, 0, stream>>>(ei, e0, n, counts);
    scan_kernel<<<1, 1024, 0, stream>>>(counts, row_ptr, cursor, n);
    scatter_kernel<<<(et + 255) / 256, 256, 0, stream>>>(ei, e0, n, cursor, src_sorted);

    // ---- operand conversion ----
    convA_kernel<<<((n * 256) + 255) / 256, blk, 0, stream>>>(x, slotA, n, 256);
    convW_kernel<<<((512 * 256) + 255) / 256, blk, 0, stream>>>(W1, WT1, 256, 512, 512);
    convW_kernel<<<((512 * 512) + 255) / 256, blk, 0, stream>>>(W2, WT2, 512, 512, 512);
    convW_kernel<<<((256 * 512) + 255) / 256, blk, 0, stream>>>(W3, WT3, 512, 256, 256);
    convW_kernel<<<((128 * 256) + 255) / 256, blk, 0, stream>>>(W4, WT4, 256, 64, 128);

    const int mblocks = Mpad / 128;   // 235
    const int zeroN = n * 8;          // as_b + ad_b contiguous

    // ---- Layer 1: K=256 -> N=512 (4 heads x 128), concat ----
    zero_float<<<(zeroN + 255) / 256, blk, 0, stream>>>(as_b, zeroN);
    gemm_mfma<<<dim3(4, mblocks), blk, 0, stream>>>(slotA, WT1, hbuf, n, 256, 512,
                                                    a1s, a1d, as_b, ad_b, 4, 128);
    agg_kernel<4, 128, true><<<nodeblocks, blk, 0, stream>>>(hbuf, as_b, ad_b, row_ptr, src_sorted, b1, nullptr, slotA, n);

    // ---- Layer 2: K=512 -> N=512 ----
    zero_float<<<(zeroN + 255) / 256, blk, 0, stream>>>(as_b, zeroN);
    gemm_mfma<<<dim3(4, mblocks), blk, 0, stream>>>(slotA, WT2, hbuf, n, 512, 512,
                                                    a2s, a2d, as_b, ad_b, 4, 128);
    agg_kernel<4, 128, true><<<nodeblocks, blk, 0, stream>>>(hbuf, as_b, ad_b, row_ptr, src_sorted, b2, nullptr, slotA, n);

    // ---- Layer 3: K=512 -> N=256 (4 heads x 64), concat ----
    zero_float<<<(zeroN + 255) / 256, blk, 0, stream>>>(as_b, zeroN);
    gemm_mfma<<<dim3(2, mblocks), blk, 0, stream>>>(slotA, WT3, hbuf, n, 512, 256,
                                                    a3s, a3d, as_b, ad_b, 4, 64);
    agg_kernel<4, 64, true><<<nodeblocks, blk, 0, stream>>>(hbuf, as_b, ad_b, row_ptr, src_sorted, b3, nullptr, slotA, n);

    // ---- Layer 4: K=256 -> N=64, 1 head, mean==identity ----
    zero_float<<<(zeroN + 255) / 256, blk, 0, stream>>>(as_b, zeroN);
    gemm_mfma<<<dim3(1, mblocks), blk, 0, stream>>>(slotA, WT4, hbuf, n, 256, 64,
                                                    a4s, a4d, as_b, ad_b, 1, 64);
    agg_kernel<1, 64, false><<<nodeblocks, blk, 0, stream>>>(hbuf, as_b, ad_b, row_ptr, src_sorted, b4, (float*)d_out, nullptr, n);
}

// Round 5
// 877.913 us; speedup vs baseline: 1.0012x; 1.0012x over previous
//
#include <hip/hip_runtime.h>
#include <math.h>

// ---------------------------------------------------------------------------
// GAT 4-layer forward.
//   CSR build (zero -> hist -> blocked scan(+cursor) -> scatter) per call.
//   Per layer: zero as/ad -> split-bf16 MFMA GEMM with fused alpha epilogue
//   -> agg kernel: pass 1 lane-parallel softmax stats (m,l), pass 2 gather
//   with precomputed alpha (4-edge unroll), epilogue emits next layer's bf16
//   hi/lo A via NON-TEMPORAL stores (keep L3 for the h gather working set).
// ---------------------------------------------------------------------------

typedef __attribute__((ext_vector_type(8))) __bf16 bf16x8;
typedef __attribute__((ext_vector_type(4))) float floatx4;
typedef __attribute__((ext_vector_type(8))) unsigned short usv8;
typedef __attribute__((ext_vector_type(4))) unsigned short usv4;

__device__ __forceinline__ unsigned short f2bf(float f) {   // RNE
    unsigned int u = __float_as_uint(f);
    u += 0x7fff + ((u >> 16) & 1);
    return (unsigned short)(u >> 16);
}
__device__ __forceinline__ float bf2f(unsigned short u) {
    return __uint_as_float(((unsigned int)u) << 16);
}
__device__ __forceinline__ float lrelu(float e) {
    return (e > 0.f) ? e : 0.2f * e;
}
__device__ __forceinline__ void gload16(const void* g, void* l) {
    __builtin_amdgcn_global_load_lds(
        (const __attribute__((address_space(1))) void*)g,
        (__attribute__((address_space(3))) void*)l, 16, 0, 0);
}

// ---------------------------------------------------------------------------
// CSR build
// ---------------------------------------------------------------------------
static __global__ void zero_int(int* __restrict__ p, int n) {
    int i = blockIdx.x * blockDim.x + threadIdx.x;
    if (i < n) p[i] = 0;
}
static __global__ void zero_float(float* __restrict__ p, int n) {
    int i = blockIdx.x * blockDim.x + threadIdx.x;
    if (i < n) p[i] = 0.f;
}

static __global__ void hist_kernel(const int* __restrict__ ei, int e0, int n_nodes,
                                   int* __restrict__ counts) {
    int e = blockIdx.x * blockDim.x + threadIdx.x;
    int et = e0 + n_nodes;
    if (e >= et) return;
    int d = (e < e0) ? ei[e0 + e] : (e - e0);
    atomicAdd(&counts[d], 1);
}

static __global__ void scan_kernel(const int* __restrict__ counts,
                                   int* __restrict__ row_ptr,
                                   int* __restrict__ cursor, int n) {
    __shared__ int sdata[1024];
    int tid = threadIdx.x;
    int per = (n + 1023) / 1024;
    int start = tid * per;
    int stop = min(start + per, n);
    if (start > n) start = n;
    int s = 0;
    for (int i = start; i < stop; i++) s += counts[i];
    sdata[tid] = s;
    __syncthreads();
    for (int off = 1; off < 1024; off <<= 1) {
        int t = (tid >= off) ? sdata[tid - off] : 0;
        __syncthreads();
        sdata[tid] += t;
        __syncthreads();
    }
    int run = sdata[tid] - s;
    for (int i = start; i < stop; i++) {
        row_ptr[i] = run;
        cursor[i] = run;
        run += counts[i];
    }
    if (stop == n) row_ptr[n] = run;
}

static __global__ void scatter_kernel(const int* __restrict__ ei, int e0, int n_nodes,
                                      int* __restrict__ cursor,
                                      int* __restrict__ src_sorted) {
    int e = blockIdx.x * blockDim.x + threadIdx.x;
    int et = e0 + n_nodes;
    if (e >= et) return;
    int s, d;
    if (e < e0) { s = ei[e]; d = ei[e0 + e]; } else { s = e - e0; d = s; }
    int pos = atomicAdd(&cursor[d], 1);
    src_sorted[pos] = s;
}

// ---------------------------------------------------------------------------
// hi/lo conversion kernels
// ---------------------------------------------------------------------------
static __global__ void convA_kernel(const float* __restrict__ X,
                                    unsigned short* __restrict__ A, int M, int K) {
    int idx = blockIdx.x * 256 + threadIdx.x;
    if (idx >= M * K) return;
    int m = idx / K, k = idx % K;
    float v = X[idx];
    unsigned short hi = f2bf(v);
    size_t base = (size_t)m * (2 * K);
    A[base + k] = hi;
    A[base + K + k] = f2bf(v - bf2f(hi));
}

static __global__ void convW_kernel(const float* __restrict__ W,
                                    unsigned short* __restrict__ BT,
                                    int K, int N, int Npad) {
    int idx = blockIdx.x * 256 + threadIdx.x;
    if (idx >= Npad * K) return;
    int n = idx / K, k = idx % K;
    float v = (n < N) ? W[(size_t)k * N + n] : 0.f;
    unsigned short hi = f2bf(v);
    unsigned short lo = f2bf(v - bf2f(hi));
    size_t base = (size_t)n * (3 * K);
    BT[base + k] = hi;
    BT[base + K + k] = hi;
    BT[base + 2 * K + k] = lo;
}

// ---------------------------------------------------------------------------
// split-bf16 MFMA GEMM + fused alpha epilogue.
// ---------------------------------------------------------------------------
#define BM 128
#define BN 128
#define BKK 64

__launch_bounds__(256)
static __global__ void gemm_mfma(const unsigned short* __restrict__ A,
                                 const unsigned short* __restrict__ B,
                                 float* __restrict__ C, int M, int K, int N,
                                 const float* __restrict__ asv,
                                 const float* __restrict__ adv,
                                 float* __restrict__ as_out,
                                 float* __restrict__ ad_out,
                                 int Hh, int Cc) {
    __shared__ __align__(16) unsigned short lds[2 * BM * BKK];   // 16KB A + 16KB B
    const int tid  = threadIdx.x;
    const int lane = tid & 63;
    const int wave = tid >> 6;
    const int r0 = blockIdx.y * BM;
    const int c0 = blockIdx.x * BN;
    const int wm = (wave >> 1) * 64;
    const int wn = (wave & 1) * 64;
    const int q   = lane >> 4;
    const int m16 = lane & 15;

    floatx4 acc[4][4];
#pragma unroll
    for (int i = 0; i < 4; i++)
#pragma unroll
        for (int j = 0; j < 4; j++) acc[i][j] = {0.f, 0.f, 0.f, 0.f};

    const size_t sA = (size_t)(2 * K);
    const size_t sB = (size_t)(3 * K);
    char* ldsb = (char*)lds;

#pragma unroll 1
    for (int seg = 0; seg < 3; seg++) {
        const int aoff = (seg == 1) ? K : 0;
        const int boff = seg * K;
#pragma unroll 1
        for (int k0 = 0; k0 < K; k0 += BKK) {
            __syncthreads();
#pragma unroll
            for (int c = 0; c < 4; c++) {
                int slot = c * 256 + tid;
                int row = slot >> 3;          // 0..127
                int gc  = (slot & 7) ^ (row & 7);
                gload16(A + (size_t)(r0 + row) * sA + aoff + k0 + gc * 8,
                        ldsb + slot * 16);
                gload16(B + (size_t)(c0 + row) * sB + boff + k0 + gc * 8,
                        ldsb + 16384 + slot * 16);
            }
            __syncthreads();
#pragma unroll
            for (int ks = 0; ks < 2; ks++) {
                bf16x8 af[4], bfr[4];
#pragma unroll
                for (int i = 0; i < 4; i++) {
                    int row = wm + i * 16 + m16;
                    int ch  = (q + ks * 4) ^ (row & 7);
                    af[i] = *(const bf16x8*)(ldsb + (row * 8 + ch) * 16);
                }
#pragma unroll
                for (int j = 0; j < 4; j++) {
                    int row = wn + j * 16 + m16;
                    int ch  = (q + ks * 4) ^ (row & 7);
                    bfr[j] = *(const bf16x8*)(ldsb + 16384 + (row * 8 + ch) * 16);
                }
#pragma unroll
                for (int i = 0; i < 4; i++)
#pragma unroll
                    for (int j = 0; j < 4; j++)
                        acc[i][j] = __builtin_amdgcn_mfma_f32_16x16x32_bf16(
                            af[i], bfr[j], acc[i][j], 0, 0, 0);
            }
        }
    }
    // C store. C/D layout: col = lane&15, row = (lane>>4)*4 + reg
#pragma unroll
    for (int i = 0; i < 4; i++)
#pragma unroll
        for (int j = 0; j < 4; j++)
#pragma unroll
            for (int r = 0; r < 4; r++) {
                int row = r0 + wm + i * 16 + q * 4 + r;
                int col = c0 + wn + j * 16 + m16;
                if (row < M && col < N) C[(size_t)row * N + col] = acc[i][j][r];
            }
    // fused alpha: this wave's 64-col chunk [c0+wn, c0+wn+64) is head-uniform.
    if (c0 + wn < N) {
        int head = (c0 + wn) / Cc;
#pragma unroll
        for (int i = 0; i < 4; i++)
#pragma unroll
            for (int r = 0; r < 4; r++) {
                float ps = 0.f, pd = 0.f;
#pragma unroll
                for (int j = 0; j < 4; j++) {
                    int c = c0 + wn + j * 16 + m16;
                    float v = acc[i][j][r];
                    ps = fmaf(v, asv[c], ps);
                    pd = fmaf(v, adv[c], pd);
                }
#pragma unroll
                for (int off = 1; off < 16; off <<= 1) {
                    ps += __shfl_xor(ps, off);
                    pd += __shfl_xor(pd, off);
                }
                if (m16 == 0) {
                    int row = r0 + wm + i * 16 + q * 4 + r;
                    if (row < M) {
                        atomicAdd(&as_out[(size_t)row * Hh + head], ps);
                        atomicAdd(&ad_out[(size_t)row * Hh + head], pd);
                    }
                }
            }
    }
}

// ---------------------------------------------------------------------------
// aggregation: one wave/node. Pass 1: lane-parallel softmax stats. Pass 2:
// gather with precomputed alpha, 4-edge unroll. Non-temporal output stores.
// ---------------------------------------------------------------------------
template <int H, int C, bool BF16OUT>
__launch_bounds__(256)
static __global__ void agg_kernel(const float* __restrict__ h,
                                  const float* __restrict__ as_arr,
                                  const float* __restrict__ ad_arr,
                                  const int* __restrict__ row_ptr,
                                  const int* __restrict__ src_sorted,
                                  const float* __restrict__ bias,
                                  float* __restrict__ outf,
                                  unsigned short* __restrict__ outb, int n_nodes) {
    constexpr int R = H * C / 64;
    constexpr int G = 64 / H;
    constexpr int K = H * C;
    int wave = threadIdx.x >> 6;
    int lane = threadIdx.x & 63;
    int n = blockIdx.x * 4 + wave;
    if (n >= n_nodes) return;
    int beg = row_ptr[n], end = row_ptr[n + 1];

    // ---- pass 1: per-head m, l (lane-parallel over edges) ----
    float ad_h[H], m_h[H], l_h[H];
#pragma unroll
    for (int hh = 0; hh < H; hh++) {
        ad_h[hh] = ad_arr[(size_t)n * H + hh];
        m_h[hh] = -INFINITY;
        l_h[hh] = 0.f;
    }
    for (int base = beg; base < end; base += 64) {
        int j = base + lane;
        bool ok = j < end;
        float e_h[H];
        if (ok) {
            int s = src_sorted[j];
            if constexpr (H == 4) {
                float4 a = ((const float4*)as_arr)[s];
                e_h[0] = lrelu(a.x + ad_h[0]);
                e_h[1] = lrelu(a.y + ad_h[1]);
                e_h[2] = lrelu(a.z + ad_h[2]);
                e_h[3] = lrelu(a.w + ad_h[3]);
            } else {
                e_h[0] = lrelu(as_arr[s] + ad_h[0]);
            }
        } else {
#pragma unroll
            for (int hh = 0; hh < H; hh++) e_h[hh] = -INFINITY;
        }
#pragma unroll
        for (int hh = 0; hh < H; hh++) {
            float cm = e_h[hh];
#pragma unroll
            for (int off = 1; off < 64; off <<= 1) cm = fmaxf(cm, __shfl_xor(cm, off));
            float newm = fmaxf(m_h[hh], cm);
            float p = ok ? __expf(e_h[hh] - newm) : 0.f;
#pragma unroll
            for (int off = 1; off < 64; off <<= 1) p += __shfl_xor(p, off);
            l_h[hh] = l_h[hh] * __expf(m_h[hh] - newm) + p;
            m_h[hh] = newm;
        }
    }
    int myh = lane / G;
    float mm, adm, inv;
    if constexpr (H == 4) {
        mm  = m_h[0];  mm  = (myh == 1) ? m_h[1] : mm;  mm  = (myh == 2) ? m_h[2] : mm;  mm  = (myh == 3) ? m_h[3] : mm;
        float ll = l_h[0]; ll = (myh == 1) ? l_h[1] : ll; ll = (myh == 2) ? l_h[2] : ll; ll = (myh == 3) ? l_h[3] : ll;
        adm = ad_h[0]; adm = (myh == 1) ? ad_h[1] : adm; adm = (myh == 2) ? ad_h[2] : adm; adm = (myh == 3) ? ad_h[3] : adm;
        inv = 1.f / ll;
    } else {
        mm = m_h[0]; adm = ad_h[0]; inv = 1.f / l_h[0];
    }

    // ---- pass 2: gather with precomputed alpha (4-edge unroll) ----
    float acc[R];
#pragma unroll
    for (int r = 0; r < R; r++) acc[r] = 0.f;

    int j = beg;
    for (; j + 3 < end; j += 4) {
        int s0 = src_sorted[j];
        int s1 = src_sorted[j + 1];
        int s2 = src_sorted[j + 2];
        int s3 = src_sorted[j + 3];
        float w0 = __expf(lrelu(as_arr[(size_t)s0 * H + myh] + adm) - mm) * inv;
        float w1 = __expf(lrelu(as_arr[(size_t)s1 * H + myh] + adm) - mm) * inv;
        float w2 = __expf(lrelu(as_arr[(size_t)s2 * H + myh] + adm) - mm) * inv;
        float w3 = __expf(lrelu(as_arr[(size_t)s3 * H + myh] + adm) - mm) * inv;
        const float* h0 = h + (size_t)s0 * K + lane * R;
        const float* h1 = h + (size_t)s1 * K + lane * R;
        const float* h2 = h + (size_t)s2 * K + lane * R;
        const float* h3 = h + (size_t)s3 * K + lane * R;
        if constexpr (R >= 4) {
#pragma unroll
            for (int qq = 0; qq < R / 4; qq++) {
                float4 v0 = ((const float4*)h0)[qq];
                float4 v1 = ((const float4*)h1)[qq];
                float4 v2 = ((const float4*)h2)[qq];
                float4 v3 = ((const float4*)h3)[qq];
                acc[qq * 4 + 0] += w0 * v0.x + w1 * v1.x + w2 * v2.x + w3 * v3.x;
                acc[qq * 4 + 1] += w0 * v0.y + w1 * v1.y + w2 * v2.y + w3 * v3.y;
                acc[qq * 4 + 2] += w0 * v0.z + w1 * v1.z + w2 * v2.z + w3 * v3.z;
                acc[qq * 4 + 3] += w0 * v0.w + w1 * v1.w + w2 * v2.w + w3 * v3.w;
            }
        } else {
#pragma unroll
            for (int r = 0; r < R; r++)
                acc[r] += w0 * h0[r] + w1 * h1[r] + w2 * h2[r] + w3 * h3[r];
        }
    }
    for (; j < end; j++) {
        int s0 = src_sorted[j];
        float w0 = __expf(lrelu(as_arr[(size_t)s0 * H + myh] + adm) - mm) * inv;
        const float* h0 = h + (size_t)s0 * K + lane * R;
        if constexpr (R >= 4) {
#pragma unroll
            for (int qq = 0; qq < R / 4; qq++) {
                float4 v0 = ((const float4*)h0)[qq];
                acc[qq * 4 + 0] += w0 * v0.x;
                acc[qq * 4 + 1] += w0 * v0.y;
                acc[qq * 4 + 2] += w0 * v0.z;
                acc[qq * 4 + 3] += w0 * v0.w;
            }
        } else {
#pragma unroll
            for (int r = 0; r < R; r++) acc[r] += w0 * h0[r];
        }
    }

    // ---- epilogue: bias + relu, non-temporal stores ----
    float vout[R];
#pragma unroll
    for (int r = 0; r < R; r++)
        vout[r] = fmaxf(acc[r] + bias[lane * R + r], 0.f);

    if constexpr (BF16OUT) {
        unsigned short hi[R], lo[R];
#pragma unroll
        for (int r = 0; r < R; r++) {
            hi[r] = f2bf(vout[r]);
            lo[r] = f2bf(vout[r] - bf2f(hi[r]));
        }
        size_t base = (size_t)n * (2 * K) + lane * R;
        if constexpr (R == 8) {
            usv8 vh = {hi[0], hi[1], hi[2], hi[3], hi[4], hi[5], hi[6], hi[7]};
            usv8 vl = {lo[0], lo[1], lo[2], lo[3], lo[4], lo[5], lo[6], lo[7]};
            __builtin_nontemporal_store(vh, (usv8*)(outb + base));
            __builtin_nontemporal_store(vl, (usv8*)(outb + base + K));
        } else if constexpr (R == 4) {
            usv4 vh = {hi[0], hi[1], hi[2], hi[3]};
            usv4 vl = {lo[0], lo[1], lo[2], lo[3]};
            __builtin_nontemporal_store(vh, (usv4*)(outb + base));
            __builtin_nontemporal_store(vl, (usv4*)(outb + base + K));
        } else {
#pragma unroll
            for (int r = 0; r < R; r++) {
                __builtin_nontemporal_store(hi[r], outb + base + r);
                __builtin_nontemporal_store(lo[r], outb + base + K + r);
            }
        }
    } else {
#pragma unroll
        for (int r = 0; r < R; r++)
            __builtin_nontemporal_store(vout[r], outf + (size_t)n * K + lane * R + r);
    }
}

// ---------------------------------------------------------------------------

static inline size_t align_up(size_t x) { return (x + 255) & ~(size_t)255; }

extern "C" void kernel_launch(void* const* d_in, const int* in_sizes, int n_in,
                              void* d_out, int out_size, void* d_ws, size_t ws_size,
                              hipStream_t stream) {
    const float* x   = (const float*)d_in[0];
    const int*   ei  = (const int*)d_in[1];
    const float* W1  = (const float*)d_in[2];
    const float* a1s = (const float*)d_in[3];
    const float* a1d = (const float*)d_in[4];
    const float* b1  = (const float*)d_in[5];
    const float* W2  = (const float*)d_in[6];
    const float* a2s = (const float*)d_in[7];
    const float* a2d = (const float*)d_in[8];
    const float* b2  = (const float*)d_in[9];
    const float* W3  = (const float*)d_in[10];
    const float* a3s = (const float*)d_in[11];
    const float* a3d = (const float*)d_in[12];
    const float* b3  = (const float*)d_in[13];
    const float* W4  = (const float*)d_in[14];
    const float* a4s = (const float*)d_in[15];
    const float* a4d = (const float*)d_in[16];
    const float* b4  = (const float*)d_in[17];

    const int n  = in_sizes[0] / 256;    // 30000
    const int e0 = in_sizes[1] / 2;      // 480000
    const int et = e0 + n;
    const int Mpad = ((n + 127) / 128) * 128;   // 30080

    // workspace layout (~130 MB)
    char* w = (char*)d_ws;
    unsigned short* slotA = (unsigned short*)w;  w += align_up((size_t)Mpad * 1024 * 2);
    float* hbuf = (float*)w;                     w += align_up((size_t)n * 512 * 4);
    unsigned short* WT1 = (unsigned short*)w;    w += align_up((size_t)512 * 768 * 2);
    unsigned short* WT2 = (unsigned short*)w;    w += align_up((size_t)512 * 1536 * 2);
    unsigned short* WT3 = (unsigned short*)w;    w += align_up((size_t)256 * 1536 * 2);
    unsigned short* WT4 = (unsigned short*)w;    w += align_up((size_t)128 * 768 * 2);
    float* as_b = (float*)w;                     w += align_up((size_t)n * 4 * 4);
    float* ad_b = (float*)w;                     w += align_up((size_t)n * 4 * 4);
    int* row_ptr = (int*)w;                      w += align_up((size_t)(n + 1) * 4);
    int* counts  = (int*)w;                      w += align_up((size_t)n * 4);
    int* cursor  = (int*)w;                      w += align_up((size_t)n * 4);
    int* src_sorted = (int*)w;                   w += align_up((size_t)et * 4);
    (void)ws_size;

    dim3 blk(256);
    int nodeblocks = (n + 3) / 4;

    // ---- CSR build ----
    zero_int<<<(n + 255) / 256, 256, 0, stream>>>(counts, n);
    hist_kernel<<<(et + 255) / 256, 256, 0, stream>>>(ei, e0, n, counts);
    scan_kernel<<<1, 1024, 0, stream>>>(counts, row_ptr, cursor, n);
    scatter_kernel<<<(et + 255) / 256, 256, 0, stream>>>(ei, e0, n, cursor, src_sorted);

    // ---- operand conversion ----
    convA_kernel<<<((n * 256) + 255) / 256, blk, 0, stream>>>(x, slotA, n, 256);
    convW_kernel<<<((512 * 256) + 255) / 256, blk, 0, stream>>>(W1, WT1, 256, 512, 512);
    convW_kernel<<<((512 * 512) + 255) / 256, blk, 0, stream>>>(W2, WT2, 512, 512, 512);
    convW_kernel<<<((256 * 512) + 255) / 256, blk, 0, stream>>>(W3, WT3, 512, 256, 256);
    convW_kernel<<<((128 * 256) + 255) / 256, blk, 0, stream>>>(W4, WT4, 256, 64, 128);

    const int mblocks = Mpad / 128;   // 235
    const int zeroN = n * 8;          // as_b + ad_b contiguous

    // ---- Layer 1: K=256 -> N=512 (4 heads x 128), concat ----
    zero_float<<<(zeroN + 255) / 256, blk, 0, stream>>>(as_b, zeroN);
    gemm_mfma<<<dim3(4, mblocks), blk, 0, stream>>>(slotA, WT1, hbuf, n, 256, 512,
                                                    a1s, a1d, as_b, ad_b, 4, 128);
    agg_kernel<4, 128, true><<<nodeblocks, blk, 0, stream>>>(hbuf, as_b, ad_b, row_ptr, src_sorted, b1, nullptr, slotA, n);

    // ---- Layer 2: K=512 -> N=512 ----
    zero_float<<<(zeroN + 255) / 256, blk, 0, stream>>>(as_b, zeroN);
    gemm_mfma<<<dim3(4, mblocks), blk, 0, stream>>>(slotA, WT2, hbuf, n, 512, 512,
                                                    a2s, a2d, as_b, ad_b, 4, 128);
    agg_kernel<4, 128, true><<<nodeblocks, blk, 0, stream>>>(hbuf, as_b, ad_b, row_ptr, src_sorted, b2, nullptr, slotA, n);

    // ---- Layer 3: K=512 -> N=256 (4 heads x 64), concat ----
    zero_float<<<(zeroN + 255) / 256, blk, 0, stream>>>(as_b, zeroN);
    gemm_mfma<<<dim3(2, mblocks), blk, 0, stream>>>(slotA, WT3, hbuf, n, 512, 256,
                                                    a3s, a3d, as_b, ad_b, 4, 64);
    agg_kernel<4, 64, true><<<nodeblocks, blk, 0, stream>>>(hbuf, as_b, ad_b, row_ptr, src_sorted, b3, nullptr, slotA, n);

    // ---- Layer 4: K=256 -> N=64, 1 head, mean==identity ----
    zero_float<<<(zeroN + 255) / 256, blk, 0, stream>>>(as_b, zeroN);
    gemm_mfma<<<dim3(1, mblocks), blk, 0, stream>>>(slotA, WT4, hbuf, n, 256, 64,
                                                    a4s, a4d, as_b, ad_b, 1, 64);
    agg_kernel<1, 64, false><<<nodeblocks, blk, 0, stream>>>(hbuf, as_b, ad_b, row_ptr, src_sorted, b4, (float*)d_out, nullptr, n);
}

// Round 6
// 673.397 us; speedup vs baseline: 1.3053x; 1.3037x over previous
//
#include <hip/hip_runtime.h>
#include <hip/hip_fp16.h>
#include <math.h>

// ---------------------------------------------------------------------------
// GAT 4-layer forward.
//   CSR build (zero -> hist -> blocked scan(+cursor) -> scatter) per call.
//   Per layer: zero as/ad -> split-bf16 MFMA GEMM (fused alpha epilogue,
//   fp16 C for layers 1-3) -> agg kernel: pass 1 lane-parallel softmax
//   stats, pass 2 fp16 gather with precomputed alpha (4-edge unroll),
//   epilogue emits next layer's bf16 hi/lo A. Layer 4 h stays fp32.
//   Rationale (R5 counters): agg is bandwidth-bound on per-XCD compulsory
//   L2 misses (FETCH ~= 8 XCD x h bytes); only shrinking h helps.
// ---------------------------------------------------------------------------

typedef __attribute__((ext_vector_type(8))) __bf16 bf16x8;
typedef __attribute__((ext_vector_type(4))) float floatx4;
typedef __attribute__((ext_vector_type(8))) unsigned short usv8;
typedef __attribute__((ext_vector_type(4))) unsigned short usv4;

__device__ __forceinline__ unsigned short f2bf(float f) {   // RNE
    unsigned int u = __float_as_uint(f);
    u += 0x7fff + ((u >> 16) & 1);
    return (unsigned short)(u >> 16);
}
__device__ __forceinline__ float bf2f(unsigned short u) {
    return __uint_as_float(((unsigned int)u) << 16);
}
__device__ __forceinline__ float lrelu(float e) {
    return (e > 0.f) ? e : 0.2f * e;
}
__device__ __forceinline__ void gload16(const void* g, void* l) {
    __builtin_amdgcn_global_load_lds(
        (const __attribute__((address_space(1))) void*)g,
        (__attribute__((address_space(3))) void*)l, 16, 0, 0);
}

// ---------------------------------------------------------------------------
// CSR build
// ---------------------------------------------------------------------------
static __global__ void zero_int(int* __restrict__ p, int n) {
    int i = blockIdx.x * blockDim.x + threadIdx.x;
    if (i < n) p[i] = 0;
}
static __global__ void zero_float(float* __restrict__ p, int n) {
    int i = blockIdx.x * blockDim.x + threadIdx.x;
    if (i < n) p[i] = 0.f;
}

static __global__ void hist_kernel(const int* __restrict__ ei, int e0, int n_nodes,
                                   int* __restrict__ counts) {
    int e = blockIdx.x * blockDim.x + threadIdx.x;
    int et = e0 + n_nodes;
    if (e >= et) return;
    int d = (e < e0) ? ei[e0 + e] : (e - e0);
    atomicAdd(&counts[d], 1);
}

static __global__ void scan_kernel(const int* __restrict__ counts,
                                   int* __restrict__ row_ptr,
                                   int* __restrict__ cursor, int n) {
    __shared__ int sdata[1024];
    int tid = threadIdx.x;
    int per = (n + 1023) / 1024;
    int start = tid * per;
    int stop = min(start + per, n);
    if (start > n) start = n;
    int s = 0;
    for (int i = start; i < stop; i++) s += counts[i];
    sdata[tid] = s;
    __syncthreads();
    for (int off = 1; off < 1024; off <<= 1) {
        int t = (tid >= off) ? sdata[tid - off] : 0;
        __syncthreads();
        sdata[tid] += t;
        __syncthreads();
    }
    int run = sdata[tid] - s;
    for (int i = start; i < stop; i++) {
        row_ptr[i] = run;
        cursor[i] = run;
        run += counts[i];
    }
    if (stop == n) row_ptr[n] = run;
}

static __global__ void scatter_kernel(const int* __restrict__ ei, int e0, int n_nodes,
                                      int* __restrict__ cursor,
                                      int* __restrict__ src_sorted) {
    int e = blockIdx.x * blockDim.x + threadIdx.x;
    int et = e0 + n_nodes;
    if (e >= et) return;
    int s, d;
    if (e < e0) { s = ei[e]; d = ei[e0 + e]; } else { s = e - e0; d = s; }
    int pos = atomicAdd(&cursor[d], 1);
    src_sorted[pos] = s;
}

// ---------------------------------------------------------------------------
// hi/lo conversion kernels
// ---------------------------------------------------------------------------
static __global__ void convA_kernel(const float* __restrict__ X,
                                    unsigned short* __restrict__ A, int M, int K) {
    int idx = blockIdx.x * 256 + threadIdx.x;
    if (idx >= M * K) return;
    int m = idx / K, k = idx % K;
    float v = X[idx];
    unsigned short hi = f2bf(v);
    size_t base = (size_t)m * (2 * K);
    A[base + k] = hi;
    A[base + K + k] = f2bf(v - bf2f(hi));
}

__device__ __forceinline__ void convW_one(const float* W, unsigned short* BT,
                                          int idx, int K, int N) {
    int n = idx / K, k = idx % K;
    float v = (n < N) ? W[(size_t)k * N + n] : 0.f;
    unsigned short hi = f2bf(v);
    unsigned short lo = f2bf(v - bf2f(hi));
    size_t base = (size_t)n * (3 * K);
    BT[base + k] = hi;
    BT[base + K + k] = hi;
    BT[base + 2 * K + k] = lo;
}

// all four weights in one dispatch
static __global__ void convW_all(const float* __restrict__ W1, unsigned short* __restrict__ BT1,
                                 const float* __restrict__ W2, unsigned short* __restrict__ BT2,
                                 const float* __restrict__ W3, unsigned short* __restrict__ BT3,
                                 const float* __restrict__ W4, unsigned short* __restrict__ BT4) {
    int idx = blockIdx.x * 256 + threadIdx.x;
    // ranges: W1 512*256, W2 512*512, W3 256*512, W4 128*256 (Npad*K)
    if (idx < 131072) { convW_one(W1, BT1, idx, 256, 512); return; }
    idx -= 131072;
    if (idx < 262144) { convW_one(W2, BT2, idx, 512, 512); return; }
    idx -= 262144;
    if (idx < 131072) { convW_one(W3, BT3, idx, 512, 256); return; }
    idx -= 131072;
    if (idx < 32768)  { convW_one(W4, BT4, idx, 256, 64); }
}

// ---------------------------------------------------------------------------
// split-bf16 MFMA GEMM + fused alpha epilogue. CF16: write C as fp16.
// ---------------------------------------------------------------------------
#define BM 128
#define BN 128
#define BKK 64

template <bool CF16>
__launch_bounds__(256)
static __global__ void gemm_mfma(const unsigned short* __restrict__ A,
                                 const unsigned short* __restrict__ B,
                                 void* __restrict__ Cv, int M, int K, int N,
                                 const float* __restrict__ asv,
                                 const float* __restrict__ adv,
                                 float* __restrict__ as_out,
                                 float* __restrict__ ad_out,
                                 int Hh, int Cc) {
    __shared__ __align__(16) unsigned short lds[2 * BM * BKK];   // 16KB A + 16KB B
    const int tid  = threadIdx.x;
    const int lane = tid & 63;
    const int wave = tid >> 6;
    const int r0 = blockIdx.y * BM;
    const int c0 = blockIdx.x * BN;
    const int wm = (wave >> 1) * 64;
    const int wn = (wave & 1) * 64;
    const int q   = lane >> 4;
    const int m16 = lane & 15;

    floatx4 acc[4][4];
#pragma unroll
    for (int i = 0; i < 4; i++)
#pragma unroll
        for (int j = 0; j < 4; j++) acc[i][j] = {0.f, 0.f, 0.f, 0.f};

    const size_t sA = (size_t)(2 * K);
    const size_t sB = (size_t)(3 * K);
    char* ldsb = (char*)lds;

#pragma unroll 1
    for (int seg = 0; seg < 3; seg++) {
        const int aoff = (seg == 1) ? K : 0;
        const int boff = seg * K;
#pragma unroll 1
        for (int k0 = 0; k0 < K; k0 += BKK) {
            __syncthreads();
#pragma unroll
            for (int c = 0; c < 4; c++) {
                int slot = c * 256 + tid;
                int row = slot >> 3;          // 0..127
                int gc  = (slot & 7) ^ (row & 7);
                gload16(A + (size_t)(r0 + row) * sA + aoff + k0 + gc * 8,
                        ldsb + slot * 16);
                gload16(B + (size_t)(c0 + row) * sB + boff + k0 + gc * 8,
                        ldsb + 16384 + slot * 16);
            }
            __syncthreads();
#pragma unroll
            for (int ks = 0; ks < 2; ks++) {
                bf16x8 af[4], bfr[4];
#pragma unroll
                for (int i = 0; i < 4; i++) {
                    int row = wm + i * 16 + m16;
                    int ch  = (q + ks * 4) ^ (row & 7);
                    af[i] = *(const bf16x8*)(ldsb + (row * 8 + ch) * 16);
                }
#pragma unroll
                for (int j = 0; j < 4; j++) {
                    int row = wn + j * 16 + m16;
                    int ch  = (q + ks * 4) ^ (row & 7);
                    bfr[j] = *(const bf16x8*)(ldsb + 16384 + (row * 8 + ch) * 16);
                }
#pragma unroll
                for (int i = 0; i < 4; i++)
#pragma unroll
                    for (int j = 0; j < 4; j++)
                        acc[i][j] = __builtin_amdgcn_mfma_f32_16x16x32_bf16(
                            af[i], bfr[j], acc[i][j], 0, 0, 0);
            }
        }
    }
    // C store. C/D layout: col = lane&15, row = (lane>>4)*4 + reg
#pragma unroll
    for (int i = 0; i < 4; i++)
#pragma unroll
        for (int j = 0; j < 4; j++)
#pragma unroll
            for (int r = 0; r < 4; r++) {
                int row = r0 + wm + i * 16 + q * 4 + r;
                int col = c0 + wn + j * 16 + m16;
                if (row < M && col < N) {
                    if constexpr (CF16) {
                        __half* C = (__half*)Cv;
                        C[(size_t)row * N + col] = __float2half(acc[i][j][r]);
                    } else {
                        float* C = (float*)Cv;
                        C[(size_t)row * N + col] = acc[i][j][r];
                    }
                }
            }
    // fused alpha: this wave's 64-col chunk [c0+wn, c0+wn+64) is head-uniform.
    if (c0 + wn < N) {
        int head = (c0 + wn) / Cc;
#pragma unroll
        for (int i = 0; i < 4; i++)
#pragma unroll
            for (int r = 0; r < 4; r++) {
                float ps = 0.f, pd = 0.f;
#pragma unroll
                for (int j = 0; j < 4; j++) {
                    int c = c0 + wn + j * 16 + m16;
                    float v = acc[i][j][r];
                    ps = fmaf(v, asv[c], ps);
                    pd = fmaf(v, adv[c], pd);
                }
#pragma unroll
                for (int off = 1; off < 16; off <<= 1) {
                    ps += __shfl_xor(ps, off);
                    pd += __shfl_xor(pd, off);
                }
                if (m16 == 0) {
                    int row = r0 + wm + i * 16 + q * 4 + r;
                    if (row < M) {
                        atomicAdd(&as_out[(size_t)row * Hh + head], ps);
                        atomicAdd(&ad_out[(size_t)row * Hh + head], pd);
                    }
                }
            }
    }
}

// ---------------------------------------------------------------------------
// gather helper: accumulate w * h[off .. off+R) into acc (fp16 or fp32 h)
// ---------------------------------------------------------------------------
template <int R, bool HF16>
__device__ __forceinline__ void accum_row(const void* hptr, size_t off, float w,
                                          float* acc) {
    if constexpr (HF16) {
        const __half* p = (const __half*)hptr + off;
        if constexpr (R == 8) {
            float4 raw = *(const float4*)p;          // 8 halves, one dwordx4
            const __half2* hp = (const __half2*)&raw;
#pragma unroll
            for (int qq = 0; qq < 4; qq++) {
                float2 f = __half22float2(hp[qq]);
                acc[2 * qq + 0] += w * f.x;
                acc[2 * qq + 1] += w * f.y;
            }
        } else if constexpr (R == 4) {
            float2 raw = *(const float2*)p;
            const __half2* hp = (const __half2*)&raw;
#pragma unroll
            for (int qq = 0; qq < 2; qq++) {
                float2 f = __half22float2(hp[qq]);
                acc[2 * qq + 0] += w * f.x;
                acc[2 * qq + 1] += w * f.y;
            }
        } else {
            acc[0] += w * __half2float(*p);
        }
    } else {
        const float* p = (const float*)hptr + off;
        if constexpr (R >= 4) {
#pragma unroll
            for (int qq = 0; qq < R / 4; qq++) {
                float4 v = ((const float4*)p)[qq];
                acc[4 * qq + 0] += w * v.x;
                acc[4 * qq + 1] += w * v.y;
                acc[4 * qq + 2] += w * v.z;
                acc[4 * qq + 3] += w * v.w;
            }
        } else {
#pragma unroll
            for (int r = 0; r < R; r++) acc[r] += w * p[r];
        }
    }
}

// ---------------------------------------------------------------------------
// aggregation: one wave/node. Pass 1: lane-parallel softmax stats. Pass 2:
// gather (fp16 h for layers 1-3) with precomputed alpha, 4-edge unroll.
// ---------------------------------------------------------------------------
template <int H, int C, bool BF16OUT, bool HF16>
__launch_bounds__(256)
static __global__ void agg_kernel(const void* __restrict__ h,
                                  const float* __restrict__ as_arr,
                                  const float* __restrict__ ad_arr,
                                  const int* __restrict__ row_ptr,
                                  const int* __restrict__ src_sorted,
                                  const float* __restrict__ bias,
                                  float* __restrict__ outf,
                                  unsigned short* __restrict__ outb, int n_nodes) {
    constexpr int R = H * C / 64;
    constexpr int G = 64 / H;
    constexpr int K = H * C;
    int wave = threadIdx.x >> 6;
    int lane = threadIdx.x & 63;
    int n = blockIdx.x * 4 + wave;
    if (n >= n_nodes) return;
    int beg = row_ptr[n], end = row_ptr[n + 1];

    // ---- pass 1: per-head m, l (lane-parallel over edges) ----
    float ad_h[H], m_h[H], l_h[H];
#pragma unroll
    for (int hh = 0; hh < H; hh++) {
        ad_h[hh] = ad_arr[(size_t)n * H + hh];
        m_h[hh] = -INFINITY;
        l_h[hh] = 0.f;
    }
    for (int base = beg; base < end; base += 64) {
        int j = base + lane;
        bool ok = j < end;
        float e_h[H];
        if (ok) {
            int s = src_sorted[j];
            if constexpr (H == 4) {
                float4 a = ((const float4*)as_arr)[s];
                e_h[0] = lrelu(a.x + ad_h[0]);
                e_h[1] = lrelu(a.y + ad_h[1]);
                e_h[2] = lrelu(a.z + ad_h[2]);
                e_h[3] = lrelu(a.w + ad_h[3]);
            } else {
                e_h[0] = lrelu(as_arr[s] + ad_h[0]);
            }
        } else {
#pragma unroll
            for (int hh = 0; hh < H; hh++) e_h[hh] = -INFINITY;
        }
#pragma unroll
        for (int hh = 0; hh < H; hh++) {
            float cm = e_h[hh];
#pragma unroll
            for (int off = 1; off < 64; off <<= 1) cm = fmaxf(cm, __shfl_xor(cm, off));
            float newm = fmaxf(m_h[hh], cm);
            float p = ok ? __expf(e_h[hh] - newm) : 0.f;
#pragma unroll
            for (int off = 1; off < 64; off <<= 1) p += __shfl_xor(p, off);
            l_h[hh] = l_h[hh] * __expf(m_h[hh] - newm) + p;
            m_h[hh] = newm;
        }
    }
    int myh = lane / G;
    float mm, adm, inv;
    if constexpr (H == 4) {
        mm  = m_h[0];  mm  = (myh == 1) ? m_h[1] : mm;  mm  = (myh == 2) ? m_h[2] : mm;  mm  = (myh == 3) ? m_h[3] : mm;
        float ll = l_h[0]; ll = (myh == 1) ? l_h[1] : ll; ll = (myh == 2) ? l_h[2] : ll; ll = (myh == 3) ? l_h[3] : ll;
        adm = ad_h[0]; adm = (myh == 1) ? ad_h[1] : adm; adm = (myh == 2) ? ad_h[2] : adm; adm = (myh == 3) ? ad_h[3] : adm;
        inv = 1.f / ll;
    } else {
        mm = m_h[0]; adm = ad_h[0]; inv = 1.f / l_h[0];
    }

    // ---- pass 2: gather with precomputed alpha (4-edge unroll) ----
    float acc[R];
#pragma unroll
    for (int r = 0; r < R; r++) acc[r] = 0.f;

    int j = beg;
    for (; j + 3 < end; j += 4) {
        int s0 = src_sorted[j];
        int s1 = src_sorted[j + 1];
        int s2 = src_sorted[j + 2];
        int s3 = src_sorted[j + 3];
        float w0 = __expf(lrelu(as_arr[(size_t)s0 * H + myh] + adm) - mm) * inv;
        float w1 = __expf(lrelu(as_arr[(size_t)s1 * H + myh] + adm) - mm) * inv;
        float w2 = __expf(lrelu(as_arr[(size_t)s2 * H + myh] + adm) - mm) * inv;
        float w3 = __expf(lrelu(as_arr[(size_t)s3 * H + myh] + adm) - mm) * inv;
        accum_row<R, HF16>(h, (size_t)s0 * K + lane * R, w0, acc);
        accum_row<R, HF16>(h, (size_t)s1 * K + lane * R, w1, acc);
        accum_row<R, HF16>(h, (size_t)s2 * K + lane * R, w2, acc);
        accum_row<R, HF16>(h, (size_t)s3 * K + lane * R, w3, acc);
    }
    for (; j < end; j++) {
        int s0 = src_sorted[j];
        float w0 = __expf(lrelu(as_arr[(size_t)s0 * H + myh] + adm) - mm) * inv;
        accum_row<R, HF16>(h, (size_t)s0 * K + lane * R, w0, acc);
    }

    // ---- epilogue: bias + relu ----
    float vout[R];
#pragma unroll
    for (int r = 0; r < R; r++)
        vout[r] = fmaxf(acc[r] + bias[lane * R + r], 0.f);

    if constexpr (BF16OUT) {
        unsigned short hi[R], lo[R];
#pragma unroll
        for (int r = 0; r < R; r++) {
            hi[r] = f2bf(vout[r]);
            lo[r] = f2bf(vout[r] - bf2f(hi[r]));
        }
        size_t base = (size_t)n * (2 * K) + lane * R;
        if constexpr (R == 8) {
            usv8 vh = {hi[0], hi[1], hi[2], hi[3], hi[4], hi[5], hi[6], hi[7]};
            usv8 vl = {lo[0], lo[1], lo[2], lo[3], lo[4], lo[5], lo[6], lo[7]};
            *(usv8*)(outb + base) = vh;
            *(usv8*)(outb + base + K) = vl;
        } else if constexpr (R == 4) {
            usv4 vh = {hi[0], hi[1], hi[2], hi[3]};
            usv4 vl = {lo[0], lo[1], lo[2], lo[3]};
            *(usv4*)(outb + base) = vh;
            *(usv4*)(outb + base + K) = vl;
        } else {
#pragma unroll
            for (int r = 0; r < R; r++) {
                outb[base + r] = hi[r];
                outb[base + K + r] = lo[r];
            }
        }
    } else {
#pragma unroll
        for (int r = 0; r < R; r++)
            outf[(size_t)n * K + lane * R + r] = vout[r];
    }
}

// ---------------------------------------------------------------------------

static inline size_t align_up(size_t x) { return (x + 255) & ~(size_t)255; }

extern "C" void kernel_launch(void* const* d_in, const int* in_sizes, int n_in,
                              void* d_out, int out_size, void* d_ws, size_t ws_size,
                              hipStream_t stream) {
    const float* x   = (const float*)d_in[0];
    const int*   ei  = (const int*)d_in[1];
    const float* W1  = (const float*)d_in[2];
    const float* a1s = (const float*)d_in[3];
    const float* a1d = (const float*)d_in[4];
    const float* b1  = (const float*)d_in[5];
    const float* W2  = (const float*)d_in[6];
    const float* a2s = (const float*)d_in[7];
    const float* a2d = (const float*)d_in[8];
    const float* b2  = (const float*)d_in[9];
    const float* W3  = (const float*)d_in[10];
    const float* a3s = (const float*)d_in[11];
    const float* a3d = (const float*)d_in[12];
    const float* b3  = (const float*)d_in[13];
    const float* W4  = (const float*)d_in[14];
    const float* a4s = (const float*)d_in[15];
    const float* a4d = (const float*)d_in[16];
    const float* b4  = (const float*)d_in[17];

    const int n  = in_sizes[0] / 256;    // 30000
    const int e0 = in_sizes[1] / 2;      // 480000
    const int et = e0 + n;
    const int Mpad = ((n + 127) / 128) * 128;   // 30080

    // workspace layout (~130 MB)
    char* w = (char*)d_ws;
    unsigned short* slotA = (unsigned short*)w;  w += align_up((size_t)Mpad * 1024 * 2);
    char* hbuf = (char*)w;                       w += align_up((size_t)n * 512 * 4);
    unsigned short* WT1 = (unsigned short*)w;    w += align_up((size_t)512 * 768 * 2);
    unsigned short* WT2 = (unsigned short*)w;    w += align_up((size_t)512 * 1536 * 2);
    unsigned short* WT3 = (unsigned short*)w;    w += align_up((size_t)256 * 1536 * 2);
    unsigned short* WT4 = (unsigned short*)w;    w += align_up((size_t)128 * 768 * 2);
    float* as_b = (float*)w;                     w += align_up((size_t)n * 4 * 4);
    float* ad_b = (float*)w;                     w += align_up((size_t)n * 4 * 4);
    int* row_ptr = (int*)w;                      w += align_up((size_t)(n + 1) * 4);
    int* counts  = (int*)w;                      w += align_up((size_t)n * 4);
    int* cursor  = (int*)w;                      w += align_up((size_t)n * 4);
    int* src_sorted = (int*)w;                   w += align_up((size_t)et * 4);
    (void)ws_size;

    dim3 blk(256);
    int nodeblocks = (n + 3) / 4;

    // ---- CSR build ----
    zero_int<<<(n + 255) / 256, 256, 0, stream>>>(counts, n);
    hist_kernel<<<(et + 255) / 256, 256, 0, stream>>>(ei, e0, n, counts);
    scan_kernel<<<1, 1024, 0, stream>>>(counts, row_ptr, cursor, n);
    scatter_kernel<<<(et + 255) / 256, 256, 0, stream>>>(ei, e0, n, cursor, src_sorted);

    // ---- operand conversion ----
    convA_kernel<<<((n * 256) + 255) / 256, blk, 0, stream>>>(x, slotA, n, 256);
    convW_all<<<(557056 + 255) / 256, blk, 0, stream>>>(W1, WT1, W2, WT2, W3, WT3, W4, WT4);

    const int mblocks = Mpad / 128;   // 235
    const int zeroN = n * 8;          // as_b + ad_b contiguous

    // ---- Layer 1: K=256 -> N=512 (4 heads x 128), concat ----
    zero_float<<<(zeroN + 255) / 256, blk, 0, stream>>>(as_b, zeroN);
    gemm_mfma<true><<<dim3(4, mblocks), blk, 0, stream>>>(slotA, WT1, hbuf, n, 256, 512,
                                                          a1s, a1d, as_b, ad_b, 4, 128);
    agg_kernel<4, 128, true, true><<<nodeblocks, blk, 0, stream>>>(hbuf, as_b, ad_b, row_ptr, src_sorted, b1, nullptr, slotA, n);

    // ---- Layer 2: K=512 -> N=512 ----
    zero_float<<<(zeroN + 255) / 256, blk, 0, stream>>>(as_b, zeroN);
    gemm_mfma<true><<<dim3(4, mblocks), blk, 0, stream>>>(slotA, WT2, hbuf, n, 512, 512,
                                                          a2s, a2d, as_b, ad_b, 4, 128);
    agg_kernel<4, 128, true, true><<<nodeblocks, blk, 0, stream>>>(hbuf, as_b, ad_b, row_ptr, src_sorted, b2, nullptr, slotA, n);

    // ---- Layer 3: K=512 -> N=256 (4 heads x 64), concat ----
    zero_float<<<(zeroN + 255) / 256, blk, 0, stream>>>(as_b, zeroN);
    gemm_mfma<true><<<dim3(2, mblocks), blk, 0, stream>>>(slotA, WT3, hbuf, n, 512, 256,
                                                          a3s, a3d, as_b, ad_b, 4, 64);
    agg_kernel<4, 64, true, true><<<nodeblocks, blk, 0, stream>>>(hbuf, as_b, ad_b, row_ptr, src_sorted, b3, nullptr, slotA, n);

    // ---- Layer 4: K=256 -> N=64, 1 head, mean==identity. fp32 h. ----
    zero_float<<<(zeroN + 255) / 256, blk, 0, stream>>>(as_b, zeroN);
    gemm_mfma<false><<<dim3(1, mblocks), blk, 0, stream>>>(slotA, WT4, hbuf, n, 256, 64,
                                                           a4s, a4d, as_b, ad_b, 1, 64);
    agg_kernel<1, 64, false, false><<<nodeblocks, blk, 0, stream>>>(hbuf, as_b, ad_b, row_ptr, src_sorted, b4, (float*)d_out, nullptr, n);
}

// Round 7
// 640.973 us; speedup vs baseline: 1.3713x; 1.0506x over previous
//
#include <hip/hip_runtime.h>
#include <hip/hip_fp16.h>
#include <math.h>

// ---------------------------------------------------------------------------
// GAT 4-layer forward.
//   CSR build (zero -> hist -> blocked scan(+cursor) -> scatter) per call.
//   Per layer: zero as/ad -> split-bf16 MFMA GEMM (hi/lo fused in ONE K-pass,
//   XCD-aware block swizzle for A reuse, fused alpha epilogue, fp16 C)
//   -> agg kernel (softmax-stats pass + fp16 gather with precomputed alpha),
//   epilogue emits next layer's bf16 hi/lo A. All 4 layers' h in fp16.
//   R6 counters: gemm was barrier-bound (MfmaUtil 20%, nothing saturated) and
//   fetched A 3x (seg-outer loop + no cross-block L2 sharing).
// ---------------------------------------------------------------------------

typedef __attribute__((ext_vector_type(8))) __bf16 bf16x8;
typedef __attribute__((ext_vector_type(4))) float floatx4;
typedef __attribute__((ext_vector_type(8))) unsigned short usv8;
typedef __attribute__((ext_vector_type(4))) unsigned short usv4;

__device__ __forceinline__ unsigned short f2bf(float f) {   // RNE
    unsigned int u = __float_as_uint(f);
    u += 0x7fff + ((u >> 16) & 1);
    return (unsigned short)(u >> 16);
}
__device__ __forceinline__ float bf2f(unsigned short u) {
    return __uint_as_float(((unsigned int)u) << 16);
}
__device__ __forceinline__ float lrelu(float e) {
    return (e > 0.f) ? e : 0.2f * e;
}
__device__ __forceinline__ void gload16(const void* g, void* l) {
    __builtin_amdgcn_global_load_lds(
        (const __attribute__((address_space(1))) void*)g,
        (__attribute__((address_space(3))) void*)l, 16, 0, 0);
}

// ---------------------------------------------------------------------------
// CSR build
// ---------------------------------------------------------------------------
static __global__ void zero_int(int* __restrict__ p, int n) {
    int i = blockIdx.x * blockDim.x + threadIdx.x;
    if (i < n) p[i] = 0;
}
static __global__ void zero_float(float* __restrict__ p, int n) {
    int i = blockIdx.x * blockDim.x + threadIdx.x;
    if (i < n) p[i] = 0.f;
}

static __global__ void hist_kernel(const int* __restrict__ ei, int e0, int n_nodes,
                                   int* __restrict__ counts) {
    int e = blockIdx.x * blockDim.x + threadIdx.x;
    int et = e0 + n_nodes;
    if (e >= et) return;
    int d = (e < e0) ? ei[e0 + e] : (e - e0);
    atomicAdd(&counts[d], 1);
}

static __global__ void scan_kernel(const int* __restrict__ counts,
                                   int* __restrict__ row_ptr,
                                   int* __restrict__ cursor, int n) {
    __shared__ int sdata[1024];
    int tid = threadIdx.x;
    int per = (n + 1023) / 1024;
    int start = tid * per;
    int stop = min(start + per, n);
    if (start > n) start = n;
    int s = 0;
    for (int i = start; i < stop; i++) s += counts[i];
    sdata[tid] = s;
    __syncthreads();
    for (int off = 1; off < 1024; off <<= 1) {
        int t = (tid >= off) ? sdata[tid - off] : 0;
        __syncthreads();
        sdata[tid] += t;
        __syncthreads();
    }
    int run = sdata[tid] - s;
    for (int i = start; i < stop; i++) {
        row_ptr[i] = run;
        cursor[i] = run;
        run += counts[i];
    }
    if (stop == n) row_ptr[n] = run;
}

static __global__ void scatter_kernel(const int* __restrict__ ei, int e0, int n_nodes,
                                      int* __restrict__ cursor,
                                      int* __restrict__ src_sorted) {
    int e = blockIdx.x * blockDim.x + threadIdx.x;
    int et = e0 + n_nodes;
    if (e >= et) return;
    int s, d;
    if (e < e0) { s = ei[e]; d = ei[e0 + e]; } else { s = e - e0; d = s; }
    int pos = atomicAdd(&cursor[d], 1);
    src_sorted[pos] = s;
}

// ---------------------------------------------------------------------------
// hi/lo conversion kernels. A'[M,2K]: [0:K)=hi [K:2K)=lo. BT'[Npad,2K]: same.
// ---------------------------------------------------------------------------
static __global__ void convA_kernel(const float* __restrict__ X,
                                    unsigned short* __restrict__ A, int M, int K) {
    int idx = blockIdx.x * 256 + threadIdx.x;
    if (idx >= M * K) return;
    int m = idx / K, k = idx % K;
    float v = X[idx];
    unsigned short hi = f2bf(v);
    size_t base = (size_t)m * (2 * K);
    A[base + k] = hi;
    A[base + K + k] = f2bf(v - bf2f(hi));
}

__device__ __forceinline__ void convW_one(const float* W, unsigned short* BT,
                                          int idx, int K, int N) {
    int n = idx / K, k = idx % K;
    float v = (n < N) ? W[(size_t)k * N + n] : 0.f;
    unsigned short hi = f2bf(v);
    size_t base = (size_t)n * (2 * K);
    BT[base + k] = hi;
    BT[base + K + k] = f2bf(v - bf2f(hi));
}

// all four weights in one dispatch
static __global__ void convW_all(const float* __restrict__ W1, unsigned short* __restrict__ BT1,
                                 const float* __restrict__ W2, unsigned short* __restrict__ BT2,
                                 const float* __restrict__ W3, unsigned short* __restrict__ BT3,
                                 const float* __restrict__ W4, unsigned short* __restrict__ BT4) {
    int idx = blockIdx.x * 256 + threadIdx.x;
    // ranges: W1 512*256, W2 512*512, W3 256*512, W4 128*256 (Npad*K)
    if (idx < 131072) { convW_one(W1, BT1, idx, 256, 512); return; }
    idx -= 131072;
    if (idx < 262144) { convW_one(W2, BT2, idx, 512, 512); return; }
    idx -= 262144;
    if (idx < 131072) { convW_one(W3, BT3, idx, 512, 256); return; }
    idx -= 131072;
    if (idx < 32768)  { convW_one(W4, BT4, idx, 256, 64); }
}

// ---------------------------------------------------------------------------
// split-bf16 MFMA GEMM, hi/lo fused in one K-pass + fused alpha epilogue.
// C fp16. Grid is 1-D with an XCD-aware swizzle: the xcols column-blocks of
// one row-tile get ids congruent mod 8 -> same XCD -> A-tile L2 reuse.
// LDS: A_hi | A_lo | B_hi | B_lo, each 128x64 bf16 (16 KB), XOR-chunk swizzle.
// ---------------------------------------------------------------------------
#define BM 128
#define BN 128
#define BKK 64

__launch_bounds__(256, 2)
static __global__ void gemm_mfma(const unsigned short* __restrict__ A,
                                 const unsigned short* __restrict__ B,
                                 __half* __restrict__ C, int M, int K, int N,
                                 int xcols, int mblocks,
                                 const float* __restrict__ asv,
                                 const float* __restrict__ adv,
                                 float* __restrict__ as_out,
                                 float* __restrict__ ad_out,
                                 int Hh, int Cc) {
    __shared__ __align__(16) unsigned short lds[4 * BM * BKK];   // 64 KB
    const int tid  = threadIdx.x;
    const int lane = tid & 63;
    const int wave = tid >> 6;

    // XCD swizzle: bands of 8 row-tiles; within a band, id = band*8*xcols +
    // x*band_rows + ry  =>  for fixed ry all x share id mod 8 (band_rows=8).
    const int id = blockIdx.x;
    const int band = id / (8 * xcols);
    const int rem = id - band * 8 * xcols;
    const int band_rows = min(8, mblocks - band * 8);
    const int ry = rem % band_rows;
    const int rx = rem / band_rows;
    const int r0 = (band * 8 + ry) * BM;
    const int c0 = rx * BN;

    const int wm = (wave >> 1) * 64;
    const int wn = (wave & 1) * 64;
    const int q   = lane >> 4;
    const int m16 = lane & 15;

    floatx4 acc[4][4];
#pragma unroll
    for (int i = 0; i < 4; i++)
#pragma unroll
        for (int j = 0; j < 4; j++) acc[i][j] = {0.f, 0.f, 0.f, 0.f};

    const size_t sA = (size_t)(2 * K);
    const size_t sB = (size_t)(2 * K);
    char* ldsb = (char*)lds;

#pragma unroll 1
    for (int k0 = 0; k0 < K; k0 += BKK) {
        __syncthreads();
#pragma unroll
        for (int c = 0; c < 4; c++) {
            int slot = c * 256 + tid;
            int row = slot >> 3;          // 0..127
            int gc  = (slot & 7) ^ (row & 7);
            const unsigned short* Ab = A + (size_t)(r0 + row) * sA + k0 + gc * 8;
            const unsigned short* Bb = B + (size_t)(c0 + row) * sB + k0 + gc * 8;
            gload16(Ab,     ldsb + slot * 16);            // A hi
            gload16(Ab + K, ldsb + 16384 + slot * 16);    // A lo
            gload16(Bb,     ldsb + 32768 + slot * 16);    // B hi
            gload16(Bb + K, ldsb + 49152 + slot * 16);    // B lo
        }
        __syncthreads();
#pragma unroll
        for (int ks = 0; ks < 2; ks++) {
            bf16x8 ah[4], al[4], bh[4], bl[4];
#pragma unroll
            for (int i = 0; i < 4; i++) {
                int row = wm + i * 16 + m16;
                int ch  = (q + ks * 4) ^ (row & 7);
                int off = (row * 8 + ch) * 16;
                ah[i] = *(const bf16x8*)(ldsb + off);
                al[i] = *(const bf16x8*)(ldsb + 16384 + off);
            }
#pragma unroll
            for (int j = 0; j < 4; j++) {
                int row = wn + j * 16 + m16;
                int ch  = (q + ks * 4) ^ (row & 7);
                int off = (row * 8 + ch) * 16;
                bh[j] = *(const bf16x8*)(ldsb + 32768 + off);
                bl[j] = *(const bf16x8*)(ldsb + 49152 + off);
            }
#pragma unroll
            for (int i = 0; i < 4; i++)
#pragma unroll
                for (int j = 0; j < 4; j++) {
                    acc[i][j] = __builtin_amdgcn_mfma_f32_16x16x32_bf16(
                        ah[i], bh[j], acc[i][j], 0, 0, 0);
                    acc[i][j] = __builtin_amdgcn_mfma_f32_16x16x32_bf16(
                        al[i], bh[j], acc[i][j], 0, 0, 0);
                    acc[i][j] = __builtin_amdgcn_mfma_f32_16x16x32_bf16(
                        ah[i], bl[j], acc[i][j], 0, 0, 0);
                }
        }
    }
    // C store (fp16). C/D layout: col = lane&15, row = (lane>>4)*4 + reg
#pragma unroll
    for (int i = 0; i < 4; i++)
#pragma unroll
        for (int j = 0; j < 4; j++)
#pragma unroll
            for (int r = 0; r < 4; r++) {
                int row = r0 + wm + i * 16 + q * 4 + r;
                int col = c0 + wn + j * 16 + m16;
                if (row < M && col < N)
                    C[(size_t)row * N + col] = __float2half(acc[i][j][r]);
            }
    // fused alpha: this wave's 64-col chunk [c0+wn, c0+wn+64) is head-uniform.
    if (c0 + wn < N) {
        int head = (c0 + wn) / Cc;
#pragma unroll
        for (int i = 0; i < 4; i++)
#pragma unroll
            for (int r = 0; r < 4; r++) {
                float ps = 0.f, pd = 0.f;
#pragma unroll
                for (int j = 0; j < 4; j++) {
                    int c = c0 + wn + j * 16 + m16;
                    float v = acc[i][j][r];
                    ps = fmaf(v, asv[c], ps);
                    pd = fmaf(v, adv[c], pd);
                }
#pragma unroll
                for (int off = 1; off < 16; off <<= 1) {
                    ps += __shfl_xor(ps, off);
                    pd += __shfl_xor(pd, off);
                }
                if (m16 == 0) {
                    int row = r0 + wm + i * 16 + q * 4 + r;
                    if (row < M) {
                        atomicAdd(&as_out[(size_t)row * Hh + head], ps);
                        atomicAdd(&ad_out[(size_t)row * Hh + head], pd);
                    }
                }
            }
    }
}

// ---------------------------------------------------------------------------
// gather helper: accumulate w * h_fp16[off .. off+R) into acc
// ---------------------------------------------------------------------------
template <int R>
__device__ __forceinline__ void accum_row(const __half* hptr, size_t off, float w,
                                          float* acc) {
    const __half* p = hptr + off;
    if constexpr (R == 8) {
        float4 raw = *(const float4*)p;          // 8 halves, one dwordx4
        const __half2* hp = (const __half2*)&raw;
#pragma unroll
        for (int qq = 0; qq < 4; qq++) {
            float2 f = __half22float2(hp[qq]);
            acc[2 * qq + 0] += w * f.x;
            acc[2 * qq + 1] += w * f.y;
        }
    } else if constexpr (R == 4) {
        float2 raw = *(const float2*)p;
        const __half2* hp = (const __half2*)&raw;
#pragma unroll
        for (int qq = 0; qq < 2; qq++) {
            float2 f = __half22float2(hp[qq]);
            acc[2 * qq + 0] += w * f.x;
            acc[2 * qq + 1] += w * f.y;
        }
    } else {
        acc[0] += w * __half2float(*p);
    }
}

// ---------------------------------------------------------------------------
// aggregation: one wave/node. Pass 1: lane-parallel softmax stats. Pass 2:
// fp16 gather with precomputed alpha, 4-edge unroll.
// ---------------------------------------------------------------------------
template <int H, int C, bool BF16OUT>
__launch_bounds__(256)
static __global__ void agg_kernel(const __half* __restrict__ h,
                                  const float* __restrict__ as_arr,
                                  const float* __restrict__ ad_arr,
                                  const int* __restrict__ row_ptr,
                                  const int* __restrict__ src_sorted,
                                  const float* __restrict__ bias,
                                  float* __restrict__ outf,
                                  unsigned short* __restrict__ outb, int n_nodes) {
    constexpr int R = H * C / 64;
    constexpr int G = 64 / H;
    constexpr int K = H * C;
    int wave = threadIdx.x >> 6;
    int lane = threadIdx.x & 63;
    int n = blockIdx.x * 4 + wave;
    if (n >= n_nodes) return;
    int beg = row_ptr[n], end = row_ptr[n + 1];

    // ---- pass 1: per-head m, l (lane-parallel over edges) ----
    float ad_h[H], m_h[H], l_h[H];
#pragma unroll
    for (int hh = 0; hh < H; hh++) {
        ad_h[hh] = ad_arr[(size_t)n * H + hh];
        m_h[hh] = -INFINITY;
        l_h[hh] = 0.f;
    }
    for (int base = beg; base < end; base += 64) {
        int j = base + lane;
        bool ok = j < end;
        float e_h[H];
        if (ok) {
            int s = src_sorted[j];
            if constexpr (H == 4) {
                float4 a = ((const float4*)as_arr)[s];
                e_h[0] = lrelu(a.x + ad_h[0]);
                e_h[1] = lrelu(a.y + ad_h[1]);
                e_h[2] = lrelu(a.z + ad_h[2]);
                e_h[3] = lrelu(a.w + ad_h[3]);
            } else {
                e_h[0] = lrelu(as_arr[s] + ad_h[0]);
            }
        } else {
#pragma unroll
            for (int hh = 0; hh < H; hh++) e_h[hh] = -INFINITY;
        }
#pragma unroll
        for (int hh = 0; hh < H; hh++) {
            float cm = e_h[hh];
#pragma unroll
            for (int off = 1; off < 64; off <<= 1) cm = fmaxf(cm, __shfl_xor(cm, off));
            float newm = fmaxf(m_h[hh], cm);
            float p = ok ? __expf(e_h[hh] - newm) : 0.f;
#pragma unroll
            for (int off = 1; off < 64; off <<= 1) p += __shfl_xor(p, off);
            l_h[hh] = l_h[hh] * __expf(m_h[hh] - newm) + p;
            m_h[hh] = newm;
        }
    }
    int myh = lane / G;
    float mm, adm, inv;
    if constexpr (H == 4) {
        mm  = m_h[0];  mm  = (myh == 1) ? m_h[1] : mm;  mm  = (myh == 2) ? m_h[2] : mm;  mm  = (myh == 3) ? m_h[3] : mm;
        float ll = l_h[0]; ll = (myh == 1) ? l_h[1] : ll; ll = (myh == 2) ? l_h[2] : ll; ll = (myh == 3) ? l_h[3] : ll;
        adm = ad_h[0]; adm = (myh == 1) ? ad_h[1] : adm; adm = (myh == 2) ? ad_h[2] : adm; adm = (myh == 3) ? ad_h[3] : adm;
        inv = 1.f / ll;
    } else {
        mm = m_h[0]; adm = ad_h[0]; inv = 1.f / l_h[0];
    }

    // ---- pass 2: gather with precomputed alpha (4-edge unroll) ----
    float acc[R];
#pragma unroll
    for (int r = 0; r < R; r++) acc[r] = 0.f;

    int j = beg;
    for (; j + 3 < end; j += 4) {
        int s0 = src_sorted[j];
        int s1 = src_sorted[j + 1];
        int s2 = src_sorted[j + 2];
        int s3 = src_sorted[j + 3];
        float w0 = __expf(lrelu(as_arr[(size_t)s0 * H + myh] + adm) - mm) * inv;
        float w1 = __expf(lrelu(as_arr[(size_t)s1 * H + myh] + adm) - mm) * inv;
        float w2 = __expf(lrelu(as_arr[(size_t)s2 * H + myh] + adm) - mm) * inv;
        float w3 = __expf(lrelu(as_arr[(size_t)s3 * H + myh] + adm) - mm) * inv;
        accum_row<R>(h, (size_t)s0 * K + lane * R, w0, acc);
        accum_row<R>(h, (size_t)s1 * K + lane * R, w1, acc);
        accum_row<R>(h, (size_t)s2 * K + lane * R, w2, acc);
        accum_row<R>(h, (size_t)s3 * K + lane * R, w3, acc);
    }
    for (; j < end; j++) {
        int s0 = src_sorted[j];
        float w0 = __expf(lrelu(as_arr[(size_t)s0 * H + myh] + adm) - mm) * inv;
        accum_row<R>(h, (size_t)s0 * K + lane * R, w0, acc);
    }

    // ---- epilogue: bias + relu ----
    float vout[R];
#pragma unroll
    for (int r = 0; r < R; r++)
        vout[r] = fmaxf(acc[r] + bias[lane * R + r], 0.f);

    if constexpr (BF16OUT) {
        unsigned short hi[R], lo[R];
#pragma unroll
        for (int r = 0; r < R; r++) {
            hi[r] = f2bf(vout[r]);
            lo[r] = f2bf(vout[r] - bf2f(hi[r]));
        }
        size_t base = (size_t)n * (2 * K) + lane * R;
        if constexpr (R == 8) {
            usv8 vh = {hi[0], hi[1], hi[2], hi[3], hi[4], hi[5], hi[6], hi[7]};
            usv8 vl = {lo[0], lo[1], lo[2], lo[3], lo[4], lo[5], lo[6], lo[7]};
            *(usv8*)(outb + base) = vh;
            *(usv8*)(outb + base + K) = vl;
        } else if constexpr (R == 4) {
            usv4 vh = {hi[0], hi[1], hi[2], hi[3]};
            usv4 vl = {lo[0], lo[1], lo[2], lo[3]};
            *(usv4*)(outb + base) = vh;
            *(usv4*)(outb + base + K) = vl;
        } else {
#pragma unroll
            for (int r = 0; r < R; r++) {
                outb[base + r] = hi[r];
                outb[base + K + r] = lo[r];
            }
        }
    } else {
#pragma unroll
        for (int r = 0; r < R; r++)
            outf[(size_t)n * K + lane * R + r] = vout[r];
    }
}

// ---------------------------------------------------------------------------

static inline size_t align_up(size_t x) { return (x + 255) & ~(size_t)255; }

extern "C" void kernel_launch(void* const* d_in, const int* in_sizes, int n_in,
                              void* d_out, int out_size, void* d_ws, size_t ws_size,
                              hipStream_t stream) {
    const float* x   = (const float*)d_in[0];
    const int*   ei  = (const int*)d_in[1];
    const float* W1  = (const float*)d_in[2];
    const float* a1s = (const float*)d_in[3];
    const float* a1d = (const float*)d_in[4];
    const float* b1  = (const float*)d_in[5];
    const float* W2  = (const float*)d_in[6];
    const float* a2s = (const float*)d_in[7];
    const float* a2d = (const float*)d_in[8];
    const float* b2  = (const float*)d_in[9];
    const float* W3  = (const float*)d_in[10];
    const float* a3s = (const float*)d_in[11];
    const float* a3d = (const float*)d_in[12];
    const float* b3  = (const float*)d_in[13];
    const float* W4  = (const float*)d_in[14];
    const float* a4s = (const float*)d_in[15];
    const float* a4d = (const float*)d_in[16];
    const float* b4  = (const float*)d_in[17];

    const int n  = in_sizes[0] / 256;    // 30000
    const int e0 = in_sizes[1] / 2;      // 480000
    const int et = e0 + n;
    const int Mpad = ((n + 127) / 128) * 128;   // 30080

    // workspace layout
    char* w = (char*)d_ws;
    unsigned short* slotA = (unsigned short*)w;  w += align_up((size_t)Mpad * 1024 * 2);
    __half* hbuf = (__half*)w;                   w += align_up((size_t)n * 512 * 4);
    unsigned short* WT1 = (unsigned short*)w;    w += align_up((size_t)512 * 512 * 2);
    unsigned short* WT2 = (unsigned short*)w;    w += align_up((size_t)512 * 1024 * 2);
    unsigned short* WT3 = (unsigned short*)w;    w += align_up((size_t)256 * 1024 * 2);
    unsigned short* WT4 = (unsigned short*)w;    w += align_up((size_t)128 * 512 * 2);
    float* as_b = (float*)w;                     w += align_up((size_t)n * 4 * 4);
    float* ad_b = (float*)w;                     w += align_up((size_t)n * 4 * 4);
    int* row_ptr = (int*)w;                      w += align_up((size_t)(n + 1) * 4);
    int* counts  = (int*)w;                      w += align_up((size_t)n * 4);
    int* cursor  = (int*)w;                      w += align_up((size_t)n * 4);
    int* src_sorted = (int*)w;                   w += align_up((size_t)et * 4);
    (void)ws_size;

    dim3 blk(256);
    int nodeblocks = (n + 3) / 4;

    // ---- CSR build ----
    zero_int<<<(n + 255) / 256, 256, 0, stream>>>(counts, n);
    hist_kernel<<<(et + 255) / 256, 256, 0, stream>>>(ei, e0, n, counts);
    scan_kernel<<<1, 1024, 0, stream>>>(counts, row_ptr, cursor, n);
    scatter_kernel<<<(et + 255) / 256, 256, 0, stream>>>(ei, e0, n, cursor, src_sorted);

    // ---- operand conversion ----
    convA_kernel<<<((n * 256) + 255) / 256, blk, 0, stream>>>(x, slotA, n, 256);
    convW_all<<<(557056 + 255) / 256, blk, 0, stream>>>(W1, WT1, W2, WT2, W3, WT3, W4, WT4);

    const int mblocks = Mpad / 128;   // 235
    const int zeroN = n * 8;          // as_b + ad_b contiguous

    // ---- Layer 1: K=256 -> N=512 (4 heads x 128), concat ----
    zero_float<<<(zeroN + 255) / 256, blk, 0, stream>>>(as_b, zeroN);
    gemm_mfma<<<dim3(4 * mblocks), blk, 0, stream>>>(slotA, WT1, hbuf, n, 256, 512, 4, mblocks,
                                                     a1s, a1d, as_b, ad_b, 4, 128);
    agg_kernel<4, 128, true><<<nodeblocks, blk, 0, stream>>>(hbuf, as_b, ad_b, row_ptr, src_sorted, b1, nullptr, slotA, n);

    // ---- Layer 2: K=512 -> N=512 ----
    zero_float<<<(zeroN + 255) / 256, blk, 0, stream>>>(as_b, zeroN);
    gemm_mfma<<<dim3(4 * mblocks), blk, 0, stream>>>(slotA, WT2, hbuf, n, 512, 512, 4, mblocks,
                                                     a2s, a2d, as_b, ad_b, 4, 128);
    agg_kernel<4, 128, true><<<nodeblocks, blk, 0, stream>>>(hbuf, as_b, ad_b, row_ptr, src_sorted, b2, nullptr, slotA, n);

    // ---- Layer 3: K=512 -> N=256 (4 heads x 64), concat ----
    zero_float<<<(zeroN + 255) / 256, blk, 0, stream>>>(as_b, zeroN);
    gemm_mfma<<<dim3(2 * mblocks), blk, 0, stream>>>(slotA, WT3, hbuf, n, 512, 256, 2, mblocks,
                                                     a3s, a3d, as_b, ad_b, 4, 64);
    agg_kernel<4, 64, true><<<nodeblocks, blk, 0, stream>>>(hbuf, as_b, ad_b, row_ptr, src_sorted, b3, nullptr, slotA, n);

    // ---- Layer 4: K=256 -> N=64, 1 head, mean==identity ----
    zero_float<<<(zeroN + 255) / 256, blk, 0, stream>>>(as_b, zeroN);
    gemm_mfma<<<dim3(1 * mblocks), blk, 0, stream>>>(slotA, WT4, hbuf, n, 256, 64, 1, mblocks,
                                                     a4s, a4d, as_b, ad_b, 1, 64);
    agg_kernel<1, 64, false><<<nodeblocks, blk, 0, stream>>>(hbuf, as_b, ad_b, row_ptr, src_sorted, b4, (float*)d_out, nullptr, n);
}

// Round 8
// 630.908 us; speedup vs baseline: 1.3932x; 1.0160x over previous
//
#include <hip/hip_runtime.h>
#include <hip/hip_fp16.h>
#include <math.h>

// ---------------------------------------------------------------------------
// GAT 4-layer forward.
//   CSR build (zero -> hist -> blocked scan(+cursor) -> scatter) per call.
//   Per layer: split-bf16 MFMA GEMM (hi/lo fused one K-pass, XCD swizzle,
//   fused alpha epilogue via atomics into double-buffered as/ad, fp16 C)
//   -> agg kernel: pass 1 computes per-edge scores e lane-parallel, caches
//   them in LDS (cap 256/node, gather fallback) while reducing m,l;
//   pass 2 gathers fp16 h rows with w = exp(e-m)/l (e from LDS, fma_mix
//   accumulate); epilogue emits next layer's bf16 hi/lo A and zeroes the
//   NEXT layer's as/ad buffer (other buffer of the ping-pong -> no race).
//   R7 counters: agg VALUBusy 48% / HBM 47% -> VALU+latency mixture; FETCH
//   243 MB == 8 XCD x fp16 h (compulsory-miss floor ~39 us at 6.3 TB/s).
// ---------------------------------------------------------------------------

typedef __attribute__((ext_vector_type(8))) __bf16 bf16x8;
typedef __attribute__((ext_vector_type(4))) float floatx4;
typedef __attribute__((ext_vector_type(8))) unsigned short usv8;
typedef __attribute__((ext_vector_type(4))) unsigned short usv4;

#define DEG_CAP 256

__device__ __forceinline__ unsigned short f2bf(float f) {   // RNE
    unsigned int u = __float_as_uint(f);
    u += 0x7fff + ((u >> 16) & 1);
    return (unsigned short)(u >> 16);
}
__device__ __forceinline__ float bf2f(unsigned short u) {
    return __uint_as_float(((unsigned int)u) << 16);
}
__device__ __forceinline__ float lrelu(float e) {
    return (e > 0.f) ? e : 0.2f * e;
}
__device__ __forceinline__ void gload16(const void* g, void* l) {
    __builtin_amdgcn_global_load_lds(
        (const __attribute__((address_space(1))) void*)g,
        (__attribute__((address_space(3))) void*)l, 16, 0, 0);
}

// ---------------------------------------------------------------------------
// CSR build
// ---------------------------------------------------------------------------
static __global__ void zero_float(float* __restrict__ p, int n) {
    int i = blockIdx.x * blockDim.x + threadIdx.x;
    if (i < n) p[i] = 0.f;
}
static __global__ void zero_int(int* __restrict__ p, int n) {
    int i = blockIdx.x * blockDim.x + threadIdx.x;
    if (i < n) p[i] = 0;
}

static __global__ void hist_kernel(const int* __restrict__ ei, int e0, int n_nodes,
                                   int* __restrict__ counts) {
    int e = blockIdx.x * blockDim.x + threadIdx.x;
    int et = e0 + n_nodes;
    if (e >= et) return;
    int d = (e < e0) ? ei[e0 + e] : (e - e0);
    atomicAdd(&counts[d], 1);
}

static __global__ void scan_kernel(const int* __restrict__ counts,
                                   int* __restrict__ row_ptr,
                                   int* __restrict__ cursor, int n) {
    __shared__ int sdata[1024];
    int tid = threadIdx.x;
    int per = (n + 1023) / 1024;
    int start = tid * per;
    int stop = min(start + per, n);
    if (start > n) start = n;
    int s = 0;
    for (int i = start; i < stop; i++) s += counts[i];
    sdata[tid] = s;
    __syncthreads();
    for (int off = 1; off < 1024; off <<= 1) {
        int t = (tid >= off) ? sdata[tid - off] : 0;
        __syncthreads();
        sdata[tid] += t;
        __syncthreads();
    }
    int run = sdata[tid] - s;
    for (int i = start; i < stop; i++) {
        row_ptr[i] = run;
        cursor[i] = run;
        run += counts[i];
    }
    if (stop == n) row_ptr[n] = run;
}

static __global__ void scatter_kernel(const int* __restrict__ ei, int e0, int n_nodes,
                                      int* __restrict__ cursor,
                                      int* __restrict__ src_sorted) {
    int e = blockIdx.x * blockDim.x + threadIdx.x;
    int et = e0 + n_nodes;
    if (e >= et) return;
    int s, d;
    if (e < e0) { s = ei[e]; d = ei[e0 + e]; } else { s = e - e0; d = s; }
    int pos = atomicAdd(&cursor[d], 1);
    src_sorted[pos] = s;
}

// ---------------------------------------------------------------------------
// hi/lo conversion kernels. A'[M,2K]: [0:K)=hi [K:2K)=lo. BT'[Npad,2K]: same.
// ---------------------------------------------------------------------------
static __global__ void convA_kernel(const float* __restrict__ X,
                                    unsigned short* __restrict__ A, int M, int K) {
    int idx = blockIdx.x * 256 + threadIdx.x;
    if (idx >= M * K) return;
    int m = idx / K, k = idx % K;
    float v = X[idx];
    unsigned short hi = f2bf(v);
    size_t base = (size_t)m * (2 * K);
    A[base + k] = hi;
    A[base + K + k] = f2bf(v - bf2f(hi));
}

__device__ __forceinline__ void convW_one(const float* W, unsigned short* BT,
                                          int idx, int K, int N) {
    int n = idx / K, k = idx % K;
    float v = (n < N) ? W[(size_t)k * N + n] : 0.f;
    unsigned short hi = f2bf(v);
    size_t base = (size_t)n * (2 * K);
    BT[base + k] = hi;
    BT[base + K + k] = f2bf(v - bf2f(hi));
}

static __global__ void convW_all(const float* __restrict__ W1, unsigned short* __restrict__ BT1,
                                 const float* __restrict__ W2, unsigned short* __restrict__ BT2,
                                 const float* __restrict__ W3, unsigned short* __restrict__ BT3,
                                 const float* __restrict__ W4, unsigned short* __restrict__ BT4) {
    int idx = blockIdx.x * 256 + threadIdx.x;
    if (idx < 131072) { convW_one(W1, BT1, idx, 256, 512); return; }
    idx -= 131072;
    if (idx < 262144) { convW_one(W2, BT2, idx, 512, 512); return; }
    idx -= 262144;
    if (idx < 131072) { convW_one(W3, BT3, idx, 512, 256); return; }
    idx -= 131072;
    if (idx < 32768)  { convW_one(W4, BT4, idx, 256, 64); }
}

// ---------------------------------------------------------------------------
// split-bf16 MFMA GEMM, hi/lo fused in one K-pass + fused alpha epilogue.
// ---------------------------------------------------------------------------
#define BM 128
#define BN 128
#define BKK 64

__launch_bounds__(256, 2)
static __global__ void gemm_mfma(const unsigned short* __restrict__ A,
                                 const unsigned short* __restrict__ B,
                                 __half* __restrict__ C, int M, int K, int N,
                                 int xcols, int mblocks,
                                 const float* __restrict__ asv,
                                 const float* __restrict__ adv,
                                 float* __restrict__ as_out,
                                 float* __restrict__ ad_out,
                                 int Hh, int Cc) {
    __shared__ __align__(16) unsigned short lds[4 * BM * BKK];   // 64 KB
    const int tid  = threadIdx.x;
    const int lane = tid & 63;
    const int wave = tid >> 6;

    const int id = blockIdx.x;
    const int band = id / (8 * xcols);
    const int rem = id - band * 8 * xcols;
    const int band_rows = min(8, mblocks - band * 8);
    const int ry = rem % band_rows;
    const int rx = rem / band_rows;
    const int r0 = (band * 8 + ry) * BM;
    const int c0 = rx * BN;

    const int wm = (wave >> 1) * 64;
    const int wn = (wave & 1) * 64;
    const int q   = lane >> 4;
    const int m16 = lane & 15;

    floatx4 acc[4][4];
#pragma unroll
    for (int i = 0; i < 4; i++)
#pragma unroll
        for (int j = 0; j < 4; j++) acc[i][j] = {0.f, 0.f, 0.f, 0.f};

    const size_t sA = (size_t)(2 * K);
    const size_t sB = (size_t)(2 * K);
    char* ldsb = (char*)lds;

#pragma unroll 1
    for (int k0 = 0; k0 < K; k0 += BKK) {
        __syncthreads();
#pragma unroll
        for (int c = 0; c < 4; c++) {
            int slot = c * 256 + tid;
            int row = slot >> 3;          // 0..127
            int gc  = (slot & 7) ^ (row & 7);
            const unsigned short* Ab = A + (size_t)(r0 + row) * sA + k0 + gc * 8;
            const unsigned short* Bb = B + (size_t)(c0 + row) * sB + k0 + gc * 8;
            gload16(Ab,     ldsb + slot * 16);            // A hi
            gload16(Ab + K, ldsb + 16384 + slot * 16);    // A lo
            gload16(Bb,     ldsb + 32768 + slot * 16);    // B hi
            gload16(Bb + K, ldsb + 49152 + slot * 16);    // B lo
        }
        __syncthreads();
#pragma unroll
        for (int ks = 0; ks < 2; ks++) {
            bf16x8 ah[4], al[4], bh[4], bl[4];
#pragma unroll
            for (int i = 0; i < 4; i++) {
                int row = wm + i * 16 + m16;
                int ch  = (q + ks * 4) ^ (row & 7);
                int off = (row * 8 + ch) * 16;
                ah[i] = *(const bf16x8*)(ldsb + off);
                al[i] = *(const bf16x8*)(ldsb + 16384 + off);
            }
#pragma unroll
            for (int j = 0; j < 4; j++) {
                int row = wn + j * 16 + m16;
                int ch  = (q + ks * 4) ^ (row & 7);
                int off = (row * 8 + ch) * 16;
                bh[j] = *(const bf16x8*)(ldsb + 32768 + off);
                bl[j] = *(const bf16x8*)(ldsb + 49152 + off);
            }
#pragma unroll
            for (int i = 0; i < 4; i++)
#pragma unroll
                for (int j = 0; j < 4; j++) {
                    acc[i][j] = __builtin_amdgcn_mfma_f32_16x16x32_bf16(
                        ah[i], bh[j], acc[i][j], 0, 0, 0);
                    acc[i][j] = __builtin_amdgcn_mfma_f32_16x16x32_bf16(
                        al[i], bh[j], acc[i][j], 0, 0, 0);
                    acc[i][j] = __builtin_amdgcn_mfma_f32_16x16x32_bf16(
                        ah[i], bl[j], acc[i][j], 0, 0, 0);
                }
        }
    }
    // C store (fp16). C/D layout: col = lane&15, row = (lane>>4)*4 + reg
#pragma unroll
    for (int i = 0; i < 4; i++)
#pragma unroll
        for (int j = 0; j < 4; j++)
#pragma unroll
            for (int r = 0; r < 4; r++) {
                int row = r0 + wm + i * 16 + q * 4 + r;
                int col = c0 + wn + j * 16 + m16;
                if (row < M && col < N)
                    C[(size_t)row * N + col] = __float2half(acc[i][j][r]);
            }
    // fused alpha: this wave's 64-col chunk [c0+wn, c0+wn+64) is head-uniform.
    if (c0 + wn < N) {
        int head = (c0 + wn) / Cc;
#pragma unroll
        for (int i = 0; i < 4; i++)
#pragma unroll
            for (int r = 0; r < 4; r++) {
                float ps = 0.f, pd = 0.f;
#pragma unroll
                for (int j = 0; j < 4; j++) {
                    int c = c0 + wn + j * 16 + m16;
                    float v = acc[i][j][r];
                    ps = fmaf(v, asv[c], ps);
                    pd = fmaf(v, adv[c], pd);
                }
#pragma unroll
                for (int off = 1; off < 16; off <<= 1) {
                    ps += __shfl_xor(ps, off);
                    pd += __shfl_xor(pd, off);
                }
                if (m16 == 0) {
                    int row = r0 + wm + i * 16 + q * 4 + r;
                    if (row < M) {
                        atomicAdd(&as_out[(size_t)row * Hh + head], ps);
                        atomicAdd(&ad_out[(size_t)row * Hh + head], pd);
                    }
                }
            }
    }
}

// ---------------------------------------------------------------------------
// gather helper: acc[r] += w * h_fp16[off+r] via fma_mix (convert folded)
// ---------------------------------------------------------------------------
template <int R>
__device__ __forceinline__ void accum_row(const __half* hptr, size_t off, float w,
                                          float* acc) {
    const __half* p = hptr + off;
    if constexpr (R == 8) {
        float4 raw = *(const float4*)p;          // 8 halves, one dwordx4
        const __half* hv = (const __half*)&raw;
#pragma unroll
        for (int r = 0; r < 8; r++) acc[r] = fmaf(__half2float(hv[r]), w, acc[r]);
    } else if constexpr (R == 4) {
        float2 raw = *(const float2*)p;
        const __half* hv = (const __half*)&raw;
#pragma unroll
        for (int r = 0; r < 4; r++) acc[r] = fmaf(__half2float(hv[r]), w, acc[r]);
    } else {
        acc[0] = fmaf(__half2float(*p), w, acc[0]);
    }
}

// ---------------------------------------------------------------------------
// aggregation: one wave/node. Pass 1 computes e per edge lane-parallel,
// caches e in LDS (DEG_CAP), reduces m,l. Pass 2: w from LDS e, fp16 gather.
// Epilogue zeroes the NEXT layer's as/ad entry (ping-pong buffer, no race).
// ---------------------------------------------------------------------------
template <int H, int C, bool BF16OUT>
__launch_bounds__(256)
static __global__ void agg_kernel(const __half* __restrict__ h,
                                  const float* __restrict__ as_arr,
                                  const float* __restrict__ ad_arr,
                                  const int* __restrict__ row_ptr,
                                  const int* __restrict__ src_sorted,
                                  const float* __restrict__ bias,
                                  float* __restrict__ outf,
                                  unsigned short* __restrict__ outb,
                                  float* __restrict__ znext_as,
                                  float* __restrict__ znext_ad, int n_nodes) {
    constexpr int R = H * C / 64;
    constexpr int G = 64 / H;
    constexpr int K = H * C;
    __shared__ float lds_e[4][DEG_CAP * H];
    int wave = threadIdx.x >> 6;
    int lane = threadIdx.x & 63;
    int n = blockIdx.x * 4 + wave;
    if (n >= n_nodes) return;
    int beg = row_ptr[n], end = row_ptr[n + 1];
    float* we = lds_e[wave];

    // ---- pass 1: per-head m, l; cache e in LDS ----
    float ad_h[H], m_h[H], l_h[H];
#pragma unroll
    for (int hh = 0; hh < H; hh++) {
        ad_h[hh] = ad_arr[(size_t)n * H + hh];
        m_h[hh] = -INFINITY;
        l_h[hh] = 0.f;
    }
    for (int base = beg; base < end; base += 64) {
        int j = base + lane;
        bool ok = j < end;
        float e_h[H];
        if (ok) {
            int s = src_sorted[j];
            if constexpr (H == 4) {
                float4 a = ((const float4*)as_arr)[s];
                e_h[0] = lrelu(a.x + ad_h[0]);
                e_h[1] = lrelu(a.y + ad_h[1]);
                e_h[2] = lrelu(a.z + ad_h[2]);
                e_h[3] = lrelu(a.w + ad_h[3]);
            } else {
                e_h[0] = lrelu(as_arr[s] + ad_h[0]);
            }
            int idx = j - beg;
            if (idx < DEG_CAP) {
                if constexpr (H == 4) {
                    *(float4*)&we[idx * 4] = make_float4(e_h[0], e_h[1], e_h[2], e_h[3]);
                } else {
                    we[idx] = e_h[0];
                }
            }
        } else {
#pragma unroll
            for (int hh = 0; hh < H; hh++) e_h[hh] = -INFINITY;
        }
#pragma unroll
        for (int hh = 0; hh < H; hh++) {
            float cm = e_h[hh];
#pragma unroll
            for (int off = 1; off < 64; off <<= 1) cm = fmaxf(cm, __shfl_xor(cm, off));
            float newm = fmaxf(m_h[hh], cm);
            float p = ok ? __expf(e_h[hh] - newm) : 0.f;
#pragma unroll
            for (int off = 1; off < 64; off <<= 1) p += __shfl_xor(p, off);
            l_h[hh] = l_h[hh] * __expf(m_h[hh] - newm) + p;
            m_h[hh] = newm;
        }
    }
    int myh = lane / G;
    float mm, adm, inv;
    if constexpr (H == 4) {
        mm  = m_h[0];  mm  = (myh == 1) ? m_h[1] : mm;  mm  = (myh == 2) ? m_h[2] : mm;  mm  = (myh == 3) ? m_h[3] : mm;
        float ll = l_h[0]; ll = (myh == 1) ? l_h[1] : ll; ll = (myh == 2) ? l_h[2] : ll; ll = (myh == 3) ? l_h[3] : ll;
        adm = ad_h[0]; adm = (myh == 1) ? ad_h[1] : adm; adm = (myh == 2) ? ad_h[2] : adm; adm = (myh == 3) ? ad_h[3] : adm;
        inv = 1.f / ll;
    } else {
        mm = m_h[0]; adm = ad_h[0]; inv = 1.f / l_h[0];
    }

    // ---- pass 2: gather, w from cached e (4-edge unroll) ----
    float acc[R];
#pragma unroll
    for (int r = 0; r < R; r++) acc[r] = 0.f;

    int j = beg;
    for (; j + 3 < end; j += 4) {
        int i0 = j - beg;
        int s0 = src_sorted[j];
        int s1 = src_sorted[j + 1];
        int s2 = src_sorted[j + 2];
        int s3 = src_sorted[j + 3];
        float e0, e1, e2, e3;
        if (i0 + 3 < DEG_CAP) {
            e0 = we[(i0 + 0) * H + myh];
            e1 = we[(i0 + 1) * H + myh];
            e2 = we[(i0 + 2) * H + myh];
            e3 = we[(i0 + 3) * H + myh];
        } else {
            e0 = lrelu(as_arr[(size_t)s0 * H + myh] + adm);
            e1 = lrelu(as_arr[(size_t)s1 * H + myh] + adm);
            e2 = lrelu(as_arr[(size_t)s2 * H + myh] + adm);
            e3 = lrelu(as_arr[(size_t)s3 * H + myh] + adm);
        }
        float w0 = __expf(e0 - mm) * inv;
        float w1 = __expf(e1 - mm) * inv;
        float w2 = __expf(e2 - mm) * inv;
        float w3 = __expf(e3 - mm) * inv;
        accum_row<R>(h, (size_t)s0 * K + lane * R, w0, acc);
        accum_row<R>(h, (size_t)s1 * K + lane * R, w1, acc);
        accum_row<R>(h, (size_t)s2 * K + lane * R, w2, acc);
        accum_row<R>(h, (size_t)s3 * K + lane * R, w3, acc);
    }
    for (; j < end; j++) {
        int i0 = j - beg;
        int s0 = src_sorted[j];
        float e0 = (i0 < DEG_CAP) ? we[i0 * H + myh]
                                  : lrelu(as_arr[(size_t)s0 * H + myh] + adm);
        float w0 = __expf(e0 - mm) * inv;
        accum_row<R>(h, (size_t)s0 * K + lane * R, w0, acc);
    }

    // ---- epilogue: bias + relu; zero next layer's as/ad ----
    if (znext_as != nullptr && lane == 0) {
        if constexpr (H == 4) {
            *(float4*)&znext_as[(size_t)n * 4] = make_float4(0.f, 0.f, 0.f, 0.f);
            *(float4*)&znext_ad[(size_t)n * 4] = make_float4(0.f, 0.f, 0.f, 0.f);
        } else {
            znext_as[n] = 0.f;
            znext_ad[n] = 0.f;
        }
    }
    float vout[R];
#pragma unroll
    for (int r = 0; r < R; r++)
        vout[r] = fmaxf(acc[r] + bias[lane * R + r], 0.f);

    if constexpr (BF16OUT) {
        unsigned short hi[R], lo[R];
#pragma unroll
        for (int r = 0; r < R; r++) {
            hi[r] = f2bf(vout[r]);
            lo[r] = f2bf(vout[r] - bf2f(hi[r]));
        }
        size_t base = (size_t)n * (2 * K) + lane * R;
        if constexpr (R == 8) {
            usv8 vh = {hi[0], hi[1], hi[2], hi[3], hi[4], hi[5], hi[6], hi[7]};
            usv8 vl = {lo[0], lo[1], lo[2], lo[3], lo[4], lo[5], lo[6], lo[7]};
            *(usv8*)(outb + base) = vh;
            *(usv8*)(outb + base + K) = vl;
        } else if constexpr (R == 4) {
            usv4 vh = {hi[0], hi[1], hi[2], hi[3]};
            usv4 vl = {lo[0], lo[1], lo[2], lo[3]};
            *(usv4*)(outb + base) = vh;
            *(usv4*)(outb + base + K) = vl;
        } else {
#pragma unroll
            for (int r = 0; r < R; r++) {
                outb[base + r] = hi[r];
                outb[base + K + r] = lo[r];
            }
        }
    } else {
#pragma unroll
        for (int r = 0; r < R; r++)
            outf[(size_t)n * K + lane * R + r] = vout[r];
    }
}

// ---------------------------------------------------------------------------

static inline size_t align_up(size_t x) { return (x + 255) & ~(size_t)255; }

extern "C" void kernel_launch(void* const* d_in, const int* in_sizes, int n_in,
                              void* d_out, int out_size, void* d_ws, size_t ws_size,
                              hipStream_t stream) {
    const float* x   = (const float*)d_in[0];
    const int*   ei  = (const int*)d_in[1];
    const float* W1  = (const float*)d_in[2];
    const float* a1s = (const float*)d_in[3];
    const float* a1d = (const float*)d_in[4];
    const float* b1  = (const float*)d_in[5];
    const float* W2  = (const float*)d_in[6];
    const float* a2s = (const float*)d_in[7];
    const float* a2d = (const float*)d_in[8];
    const float* b2  = (const float*)d_in[9];
    const float* W3  = (const float*)d_in[10];
    const float* a3s = (const float*)d_in[11];
    const float* a3d = (const float*)d_in[12];
    const float* b3  = (const float*)d_in[13];
    const float* W4  = (const float*)d_in[14];
    const float* a4s = (const float*)d_in[15];
    const float* a4d = (const float*)d_in[16];
    const float* b4  = (const float*)d_in[17];

    const int n  = in_sizes[0] / 256;    // 30000
    const int e0 = in_sizes[1] / 2;      // 480000
    const int et = e0 + n;
    const int Mpad = ((n + 127) / 128) * 128;   // 30080

    // workspace layout
    char* w = (char*)d_ws;
    unsigned short* slotA = (unsigned short*)w;  w += align_up((size_t)Mpad * 1024 * 2);
    __half* hbuf = (__half*)w;                   w += align_up((size_t)n * 512 * 4);
    unsigned short* WT1 = (unsigned short*)w;    w += align_up((size_t)512 * 512 * 2);
    unsigned short* WT2 = (unsigned short*)w;    w += align_up((size_t)512 * 1024 * 2);
    unsigned short* WT3 = (unsigned short*)w;    w += align_up((size_t)256 * 1024 * 2);
    unsigned short* WT4 = (unsigned short*)w;    w += align_up((size_t)128 * 512 * 2);
    float* asA = (float*)w;                      w += align_up((size_t)n * 4 * 4);
    float* adA = (float*)w;                      w += align_up((size_t)n * 4 * 4);
    float* asB = (float*)w;                      w += align_up((size_t)n * 4 * 4);
    float* adB = (float*)w;                      w += align_up((size_t)n * 4 * 4);
    int* row_ptr = (int*)w;                      w += align_up((size_t)(n + 1) * 4);
    int* counts  = (int*)w;                      w += align_up((size_t)n * 4);
    int* cursor  = (int*)w;                      w += align_up((size_t)n * 4);
    int* src_sorted = (int*)w;                   w += align_up((size_t)et * 4);
    (void)ws_size;

    dim3 blk(256);
    int nodeblocks = (n + 3) / 4;

    // ---- CSR build ----
    zero_int<<<(n + 255) / 256, 256, 0, stream>>>(counts, n);
    hist_kernel<<<(et + 255) / 256, 256, 0, stream>>>(ei, e0, n, counts);
    scan_kernel<<<1, 1024, 0, stream>>>(counts, row_ptr, cursor, n);
    scatter_kernel<<<(et + 255) / 256, 256, 0, stream>>>(ei, e0, n, cursor, src_sorted);

    // ---- operand conversion + zero of layer-1 as/ad (asA,adA contiguous) ----
    convA_kernel<<<((n * 256) + 255) / 256, blk, 0, stream>>>(x, slotA, n, 256);
    convW_all<<<(557056 + 255) / 256, blk, 0, stream>>>(W1, WT1, W2, WT2, W3, WT3, W4, WT4);
    zero_float<<<(n * 8 + 255) / 256, blk, 0, stream>>>(asA, n * 8);

    const int mblocks = Mpad / 128;   // 235

    // ---- Layer 1: K=256 -> N=512 (4 heads x 128) ----  (A buf; agg zeroes B)
    gemm_mfma<<<dim3(4 * mblocks), blk, 0, stream>>>(slotA, WT1, hbuf, n, 256, 512, 4, mblocks,
                                                     a1s, a1d, asA, adA, 4, 128);
    agg_kernel<4, 128, true><<<nodeblocks, blk, 0, stream>>>(hbuf, asA, adA, row_ptr, src_sorted, b1, nullptr, slotA, asB, adB, n);

    // ---- Layer 2: K=512 -> N=512 ----  (B buf; agg zeroes A)
    gemm_mfma<<<dim3(4 * mblocks), blk, 0, stream>>>(slotA, WT2, hbuf, n, 512, 512, 4, mblocks,
                                                     a2s, a2d, asB, adB, 4, 128);
    agg_kernel<4, 128, true><<<nodeblocks, blk, 0, stream>>>(hbuf, asB, adB, row_ptr, src_sorted, b2, nullptr, slotA, asA, adA, n);

    // ---- Layer 3: K=512 -> N=256 (4 heads x 64) ----  (A buf; agg zeroes B)
    gemm_mfma<<<dim3(2 * mblocks), blk, 0, stream>>>(slotA, WT3, hbuf, n, 512, 256, 2, mblocks,
                                                     a3s, a3d, asA, adA, 4, 64);
    agg_kernel<4, 64, true><<<nodeblocks, blk, 0, stream>>>(hbuf, asA, adA, row_ptr, src_sorted, b3, nullptr, slotA, asB, adB, n);

    // ---- Layer 4: K=256 -> N=64, 1 head ----  (B buf; no next layer)
    gemm_mfma<<<dim3(1 * mblocks), blk, 0, stream>>>(slotA, WT4, hbuf, n, 256, 64, 1, mblocks,
                                                     a4s, a4d, asB, adB, 1, 64);
    agg_kernel<1, 64, false><<<nodeblocks, blk, 0, stream>>>(hbuf, asB, adB, row_ptr, src_sorted, b4, (float*)d_out, nullptr, nullptr, nullptr, n);
}